// Round 5
// baseline (147.982 us; speedup 1.0000x reference)
//
#include <hip/hip_runtime.h>
#include <hip/hip_bf16.h>

// AdaBiD R11: 2-kernel pipeline. MI355X gfx950.
// B=8, T=12, N=1536, H=64, TH=768, HID2=128, T_OUT=12.
//  K1 prep_all (unchanged from R10): [0,192) softmax 4 thr/row, [192,290)
//               weight repack, 290 smalls + flag.
//  K2 klmlp: fused KL + 6-layer MLP per 16-row tile, now 512 THREADS / 8 WAVES
//               per block: Phase B j-split 8x (192 j's per wave, 6 paired
//               tiles), Phase C one col-tile per wave for N=128 layers,
//               eproj K-split across wave pairs, dw3/dproj chunks on waves
//               0-3/4-5. 24 waves/CU (vs 12) for latency hiding. red2 folded
//               into the T/zf LDS union (temporally disjoint) -> 46KB LDS,
//               3 blocks/CU retained.

namespace {

constexpr int Nn = 1536, TOUT = 12;

typedef __attribute__((ext_vector_type(8))) short bf8;
typedef __attribute__((ext_vector_type(4))) float f4;
typedef unsigned short ush;

__device__ __forceinline__ float b2f(__hip_bfloat16 v) { return __bfloat162float(v); }
__device__ __forceinline__ ush f2bu(float f) {
  union { __hip_bfloat16 h; ush u; } c; c.h = __float2bfloat16(f); return c.u;
}
__device__ __forceinline__ float bu2f(ush u) {
  union { unsigned int i; float f; } c; c.i = ((unsigned)u) << 16; return c.f;
}
__device__ __forceinline__ float ldraw(const void* p, size_t i, int fl) {
  return fl ? ((const float*)p)[i] : b2f(((const __hip_bfloat16*)p)[i]);
}

// block-local dtype sniff: bf16 N(0,1) never has exp-field >= 140; f32 read
// as ushorts has ~45% of low-halves >= 140.
__device__ __forceinline__ int detect_fl(const void* x, int tid, int nthr) {
  __shared__ int cnt;
  if (tid == 0) cnt = 0;
  __syncthreads();
  const ush* u = (const ush*)x;
  int c = 0;
  for (int s = tid; s < 4096; s += nthr) {
    ush v = u[s];
    if (((v >> 7) & 0xFF) >= 140) c++;
  }
  atomicAdd(&cnt, c);
  __syncthreads();
  return (cnt > 64) ? 1 : 0;
}

struct SmallTab { const void* src[16]; int n[16]; int off[16]; };
struct RepTab { const void* src[8]; int Nc[8]; int NCT[8]; int lb[9]; };

// ---------------- K1: prep + repack + smalls ---------------------------------
__global__ __launch_bounds__(256) void prep_all(
    const void* __restrict__ xraw, SmallTab st, RepTab rt,
    int* __restrict__ flag, float* __restrict__ CS,
    float* __restrict__ sd,
    ush* __restrict__ phi16, ush* __restrict__ plo16,
    ush* __restrict__ lhi16, ush* __restrict__ llo16,
    ush* __restrict__ Xc, ush* __restrict__ Wf) {
  __shared__ float lvs[64][12];
  int tid = threadIdx.x;
  int fl = detect_fl(xraw, tid, 256);
  int blk = blockIdx.x;

  if (blk < 192) {
    // ---- prep role: 64 rows/block, 4 threads per row ----
    int rl = tid >> 2, sub = tid & 3;
    int row = blk * 64 + rl;
    int b = row / Nn, nn = row - b * Nn;   // 24 blocks/batch, no straddle
    float xv[12];
#pragma unroll
    for (int t = 0; t < 12; ++t)
      xv[t] = ldraw(xraw, (size_t)(b * 12 + t) * Nn + nn, fl);
    // redundant per-sub, bit-identical sequential order
    float mx = xv[0];
#pragma unroll
    for (int t = 1; t < 12; ++t) mx = fmaxf(mx, xv[t]);
    float e[12], Z = 0.f;
#pragma unroll
    for (int t = 0; t < 12; ++t) { e[t] = expf(xv[t] - mx); Z += e[t]; }
    float invZ = 1.f / Z;
    // each sub owns t = sub*3 .. sub*3+2: log + splits + stores
#pragma unroll
    for (int u = 0; u < 3; ++u) {
      int t = sub * 3 + u;
      float pv = e[t] * invZ;
      float lv = logf(pv + 1e-10f);
      lvs[rl][t] = lv;
      ush phv = f2bu(pv);  float plv = pv - bu2f(phv);
      ush lhv = f2bu(lv);  float llv = lv - bu2f(lhv);
      phi16[(size_t)row * 16 + t] = phv;
      plo16[(size_t)row * 16 + t] = f2bu(plv);
      lhi16[(size_t)row * 16 + t] = lhv;
      llo16[(size_t)row * 16 + t] = f2bu(llv);
      Xc[((size_t)(b * 16 + t)) * Nn + nn] = f2bu(xv[t]);
    }
    {  // pads: t = 12+sub for all arrays; Xc ones col at t=12
      int t = 12 + sub;
      phi16[(size_t)row * 16 + t] = 0;
      plo16[(size_t)row * 16 + t] = 0;
      lhi16[(size_t)row * 16 + t] = 0;
      llo16[(size_t)row * 16 + t] = 0;
      Xc[((size_t)(b * 16 + t)) * Nn + nn] = (sub == 0) ? (ush)0x3F80 : (ush)0;
    }
    __syncthreads();
    if (sub == 0) {
      float sacc = 0.f;
#pragma unroll
      for (int t = 0; t < 12; ++t)
        sacc = fmaf(e[t] * invZ, lvs[rl][t], sacc);
      sd[row] = sacc;
    }
  } else if (blk < 290) {
    // ---- repack role: weights -> MFMA B-frag order ----
    int idx = (blk - 192) * 256 + tid;
    if (idx >= rt.lb[8]) return;
    int mi = 0;
#pragma unroll
    for (int i = 1; i < 8; ++i) if (idx >= rt.lb[i]) mi = i;
    int li = idx - rt.lb[mi];
    int NCT = rt.NCT[mi], Nc = rt.Nc[mi];
    int per = NCT * 64;
    int c0 = li / per, rem = li - c0 * per;
    int ct = rem >> 6, l = rem & 63;
    int q = l >> 4, m = l & 15;
    int col = ct * 16 + m;
    ush* d = Wf + (size_t)idx * 8;
#pragma unroll
    for (int j = 0; j < 8; ++j) {
      int k = c0 * 32 + q * 8 + j;
      d[j] = (col < Nc) ? f2bu(ldraw(rt.src[mi], (size_t)k * Nc + col, fl)) : 0;
    }
  } else {
    // ---- smalls role: canonicalize biases/BN params to f32 + publish flag ----
    for (int i = 0; i < 16; ++i)
      for (int e = tid; e < st.n[i]; e += 256)
        CS[st.off[i] + e] = ldraw(st.src[i], e, fl);
    if (tid == 0) flag[0] = fl;
  }
}

// ---------------- K2: fused KL + MLP, 8 waves / 16-row tile ------------------
__global__ __launch_bounds__(512, 4) void klmlp(
    const void* __restrict__ xraw,
    const ush* __restrict__ phi16, const ush* __restrict__ plo16,
    const ush* __restrict__ lhi16, const ush* __restrict__ llo16,
    const ush* __restrict__ Xc, const float* __restrict__ sd,
    const float* __restrict__ CS, const ush* __restrict__ Wf,
    const int* __restrict__ flag, void* __restrict__ outp) {
  __shared__ float xs[16][12], ccs[16][12];
  __shared__ float sfs[16][16], sbs[16][16];
  __shared__ float ws1[64], ws2[64];
  __shared__ ush hf[2048], hg[2048], xf[1024];
  __shared__ f4 red[8][64];
  // T (16KB) + red2 (8KB) are temporally disjoint from zf (24KB): red2 is
  // written after the last T read; zf overwrites both only after the
  // reduction has consumed red2.
  __shared__ union {
    struct { ush T[2][8][512]; f4 red2[8][64]; } pb;
    ush zf[12288];
  } u;

  int tid = threadIdx.x, w = tid >> 6, l = tid & 63, q = l >> 4, n = l & 15;
  int bi = blockIdx.x;
  int r0 = bi * 16;
  int b = bi / 96;            // 96 blocks per batch (1536/16)
  int rowb = b * Nn;
  int fl = flag[0];

  // xs staging overlaps phase B (independent loads)
  if (tid < 192) {
    int rr = tid / 12, tt = tid - rr * 12;
    xs[rr][tt] = ldraw(xraw, (size_t)(b * 12 + tt) * Nn + (r0 - rowb + rr), fl);
  }

  // ================= Phase B: KL + aggregation, 8 waves split j =============
  {
    bf8 z8 = {0, 0, 0, 0, 0, 0, 0, 0};
    // A-frags straight from the hi/lo row arrays: k<16 -> hi, k>=16 -> lo
    bf8 aP = (q < 2)
        ? *(const bf8*)(phi16 + ((size_t)(r0 + n)) * 16 + q * 8)
        : *(const bf8*)(plo16 + ((size_t)(r0 + n)) * 16 + (q - 2) * 8);
    bf8 aL = (q < 2)
        ? *(const bf8*)(lhi16 + ((size_t)(r0 + n)) * 16 + q * 8)
        : *(const bf8*)(llo16 + ((size_t)(r0 + n)) * 16 + (q - 2) * 8);
    bf8 aPh = (q < 2) ? aP : z8;
    bf8 aLh = (q < 2) ? aL : z8;
    float selfI[4];
#pragma unroll
    for (int r = 0; r < 4; ++r) selfI[r] = sd[r0 + q * 4 + r];

    f4 accF = {0.f, 0.f, 0.f, 0.f}, accB = {0.f, 0.f, 0.f, 0.f};

    for (int jp = 0; jp < 6; ++jp) {
      int jl = w * 192 + jp * 32;
#pragma unroll
      for (int hh = 0; hh < 2; ++hh) {
        int jh = jl + hh * 16;
        size_t bb = ((size_t)(rowb + jh + n)) * 16 + (q & 1) * 8;
        bf8 bLh = *(const bf8*)(lhi16 + bb);
        bf8 bLo = *(const bf8*)(llo16 + bb);
        bf8 bPh = *(const bf8*)(phi16 + bb);
        bf8 bPo = *(const bf8*)(plo16 + bb);
        float selfJ = sd[rowb + jh + n];

        f4 s1 = {0.f, 0.f, 0.f, 0.f}, s2 = {0.f, 0.f, 0.f, 0.f};
        s1 = __builtin_amdgcn_mfma_f32_16x16x32_bf16(aP, bLh, s1, 0, 0, 0);
        s1 = __builtin_amdgcn_mfma_f32_16x16x32_bf16(aPh, bLo, s1, 0, 0, 0);
        s2 = __builtin_amdgcn_mfma_f32_16x16x32_bf16(aL, bPh, s2, 0, 0, 0);
        s2 = __builtin_amdgcn_mfma_f32_16x16x32_bf16(aLh, bPo, s2, 0, 0, 0);

        int qk = n >> 3, kj = n & 7;
#pragma unroll
        for (int r = 0; r < 4; ++r) {
          int pos = hh * 256 + (qk * 16 + q * 4 + r) * 8 + kj;
          u.pb.T[0][w][pos] = (selfI[r] - s1[r] < 0.5f) ? (ush)0x3F80 : (ush)0;
          u.pb.T[1][w][pos] = (selfJ - s2[r] < 0.5f) ? (ush)0x3F80 : (ush)0;
        }
      }
      bf8 af1 = *(const bf8*)(&u.pb.T[0][w][(size_t)l * 8]);
      bf8 af2 = *(const bf8*)(&u.pb.T[1][w][(size_t)l * 8]);
      bf8 xfr = *(const bf8*)(Xc + ((size_t)(b * 16 + n)) * Nn + jl + q * 8);
      accF = __builtin_amdgcn_mfma_f32_16x16x32_bf16(af1, xfr, accF, 0, 0, 0);
      accB = __builtin_amdgcn_mfma_f32_16x16x32_bf16(af2, xfr, accB, 0, 0, 0);
    }
    red[w][l] = accF;
    u.pb.red2[w][l] = accB;
  }
  __syncthreads();

  // j-split reduction -> sfs/sbs; waves 2,3 stage W1/W2 meanwhile
  if (w == 0) {
    f4 s = red[0][l] + red[1][l] + red[2][l] + red[3][l]
         + red[4][l] + red[5][l] + red[6][l] + red[7][l];
#pragma unroll
    for (int r = 0; r < 4; ++r) sfs[q * 4 + r][n] = s[r];
  } else if (w == 1) {
    f4 s = u.pb.red2[0][l] + u.pb.red2[1][l] + u.pb.red2[2][l] + u.pb.red2[3][l]
         + u.pb.red2[4][l] + u.pb.red2[5][l] + u.pb.red2[6][l] + u.pb.red2[7][l];
#pragma unroll
    for (int r = 0; r < 4; ++r) sbs[q * 4 + r][n] = s[r];
  } else if (w == 2) {
    ws1[l] = CS[l];
  } else if (w == 3) {
    ws2[l] = CS[64 + l];
  }
  __syncthreads();
  if (tid < 192) {
    int rr = tid / 12, tt = tid - rr * 12;
    float irs = 1.f / fmaxf(sfs[rr][12], 1e-6f);
    float ics = 1.f / fmaxf(sbs[rr][12], 1e-6f);
    ccs[rr][tt] = 3.0f * (0.3f * sfs[rr][tt] * irs + 0.7f * sbs[rr][tt] * ics);
  }
  __syncthreads();

  // ================= Phase C: fused MLP ====================================
  // z A-frag regen: row = r0+n, k = c0*32 + q*8 + j
  auto zregen = [&](int c0) -> bf8 {
    int t = c0 >> 1, h0 = (c0 & 1) * 32 + q * 8;
    float xv = xs[n][t], cv = ccs[n][t];
    union { bf8 v; ush uu[8]; } au;
#pragma unroll
    for (int j = 0; j < 8; ++j)
      au.uu[j] = f2bu(fmaxf(fmaf(xv, ws1[h0 + j], cv * ws2[h0 + j]), 0.f));
    return au.v;
  };
  auto fpos = [&](int ct, int r) -> int {
    return ((ct >> 1) * 64 + ((ct & 1) * 2 + (n >> 3)) * 16 + q * 4 + r) * 8 + (n & 7);
  };

  // fill the z-frag cache (overwrites T/red2; reduction done): wave w owns 3
#pragma unroll
  for (int u3 = 0; u3 < 3; ++u3) {
    int c0 = w * 3 + u3;
    bf8 v = zregen(c0);
    *(bf8*)(&u.zf[((size_t)c0 * 64 + l) * 8]) = v;
  }
  __syncthreads();

  // --- L1e: h1 = relu(z @ ew1 + b1), N=128, wave does ct = w ---------------
  {
    f4 a0 = {0.f, 0.f, 0.f, 0.f};
    for (int c0 = 0; c0 < 24; ++c0) {
      bf8 a = *(const bf8*)(&u.zf[((size_t)c0 * 64 + l) * 8]);
      bf8 b0 = *(const bf8*)(Wf + ((size_t)(c0 * 8 + w) * 64 + l) * 8);
      a0 = __builtin_amdgcn_mfma_f32_16x16x32_bf16(a, b0, a0, 0, 0, 0);
    }
    float bz = CS[128 + w * 16 + n];
#pragma unroll
    for (int r = 0; r < 4; ++r)
      hf[fpos(w, r)] = f2bu(fmaxf(a0[r] + bz, 0.f));
  }
  __syncthreads();

  // --- L2e: h2 = relu(h1 @ ew2 + b2), K=128, wave does ct = w --------------
  {
    f4 a0 = {0.f, 0.f, 0.f, 0.f};
    for (int c0 = 0; c0 < 4; ++c0) {
      bf8 a = *(const bf8*)(&hf[(size_t)(c0 * 64 + l) * 8]);
      bf8 b0 = *(const bf8*)(Wf + 98304 + ((size_t)(c0 * 8 + w) * 64 + l) * 8);
      a0 = __builtin_amdgcn_mfma_f32_16x16x32_bf16(a, b0, a0, 0, 0, 0);
    }
    __syncthreads();   // hf reads complete before later rewrite (L1d)
    float bz = CS[256 + w * 16 + n];
#pragma unroll
    for (int r = 0; r < 4; ++r)
      hg[fpos(w, r)] = f2bu(fmaxf(a0[r] + bz, 0.f));
  }
  __syncthreads();

  // --- L3e: xe = BN(h2 @ ew3 + b3 + z @ eproj), N=64 -----------------------
  // waves 0-3: ew3 (K=128) + eproj c0 0..11; waves 4-7: eproj c0 12..23.
  {
    f4 a3 = {0.f, 0.f, 0.f, 0.f};
    if (w < 4) {
      for (int c0 = 0; c0 < 4; ++c0) {
        bf8 a = *(const bf8*)(&hg[(size_t)(c0 * 64 + l) * 8]);
        bf8 bb = *(const bf8*)(Wf + 114688 + ((size_t)(c0 * 4 + w) * 64 + l) * 8);
        a3 = __builtin_amdgcn_mfma_f32_16x16x32_bf16(a, bb, a3, 0, 0, 0);
      }
      for (int c0 = 0; c0 < 12; ++c0) {
        bf8 a = *(const bf8*)(&u.zf[((size_t)c0 * 64 + l) * 8]);
        bf8 bb = *(const bf8*)(Wf + 122880 + ((size_t)(c0 * 4 + w) * 64 + l) * 8);
        a3 = __builtin_amdgcn_mfma_f32_16x16x32_bf16(a, bb, a3, 0, 0, 0);
      }
    } else {
      for (int c0 = 12; c0 < 24; ++c0) {
        bf8 a = *(const bf8*)(&u.zf[((size_t)c0 * 64 + l) * 8]);
        bf8 bb = *(const bf8*)(Wf + 122880 + ((size_t)(c0 * 4 + (w - 4)) * 64 + l) * 8);
        a3 = __builtin_amdgcn_mfma_f32_16x16x32_bf16(a, bb, a3, 0, 0, 0);
      }
    }
    red[w][l] = a3;
  }
  __syncthreads();
  if (w < 4) {
    f4 s = red[w][l] + red[w + 4][l];
    int col = w * 16 + n;
    float g = CS[448 + col], be = CS[512 + col], mm = CS[576 + col], vv = CS[640 + col];
    float sc = g / sqrtf(vv + 1e-5f);
    float sh = be - mm * sc;
    float bz = CS[384 + col];
#pragma unroll
    for (int r = 0; r < 4; ++r)
      xf[fpos(w, r)] = f2bu((s[r] + bz) * sc + sh);
  }
  __syncthreads();

  // --- L1d: g1 = relu(xe @ dw1 + b1), K=64, N=128, wave does ct = w --------
  {
    f4 a0 = {0.f, 0.f, 0.f, 0.f};
    for (int c0 = 0; c0 < 2; ++c0) {
      bf8 a = *(const bf8*)(&xf[(size_t)(c0 * 64 + l) * 8]);
      bf8 b0 = *(const bf8*)(Wf + 172032 + ((size_t)(c0 * 8 + w) * 64 + l) * 8);
      a0 = __builtin_amdgcn_mfma_f32_16x16x32_bf16(a, b0, a0, 0, 0, 0);
    }
    __syncthreads();   // hf rewrite fence
    float bz = CS[704 + w * 16 + n];
#pragma unroll
    for (int r = 0; r < 4; ++r)
      hf[fpos(w, r)] = f2bu(fmaxf(a0[r] + bz, 0.f));
  }
  __syncthreads();

  // --- L2d: g2 = relu(g1 @ dw2 + b2), K=128, wave does ct = w --------------
  {
    f4 a0 = {0.f, 0.f, 0.f, 0.f};
    for (int c0 = 0; c0 < 4; ++c0) {
      bf8 a = *(const bf8*)(&hf[(size_t)(c0 * 64 + l) * 8]);
      bf8 b0 = *(const bf8*)(Wf + 180224 + ((size_t)(c0 * 8 + w) * 64 + l) * 8);
      a0 = __builtin_amdgcn_mfma_f32_16x16x32_bf16(a, b0, a0, 0, 0, 0);
    }
    __syncthreads();   // hg rewrite fence
    float bz = CS[832 + w * 16 + n];
#pragma unroll
    for (int r = 0; r < 4; ++r)
      hg[fpos(w, r)] = f2bu(fmaxf(a0[r] + bz, 0.f));
  }
  __syncthreads();

  // --- L3d: out = BN(g2 @ dw3 + b3 + xe @ dproj), N=12; K-split ------------
  // waves 0-3: dw3 chunk c0 = w (K=128); waves 4,5: dproj chunk c0 = w-4.
  {
    f4 ao = {0.f, 0.f, 0.f, 0.f};
    if (w < 4) {
      bf8 a = *(const bf8*)(&hg[(size_t)(w * 64 + l) * 8]);
      bf8 bb = *(const bf8*)(Wf + 196608 + ((size_t)w * 64 + l) * 8);
      ao = __builtin_amdgcn_mfma_f32_16x16x32_bf16(a, bb, ao, 0, 0, 0);
    } else if (w < 6) {
      bf8 a = *(const bf8*)(&xf[(size_t)((w - 4) * 64 + l) * 8]);
      bf8 bb = *(const bf8*)(Wf + 198656 + ((size_t)(w - 4) * 64 + l) * 8);
      ao = __builtin_amdgcn_mfma_f32_16x16x32_bf16(a, bb, ao, 0, 0, 0);
    }
    red[w][l] = ao;
  }
  __syncthreads();
  if (w == 0) {
    f4 s = red[0][l] + red[1][l] + red[2][l] + red[3][l] + red[4][l] + red[5][l];
    if (n < 12) {
      float bz = CS[960 + n];
      float g = CS[972 + n], be = CS[984 + n], mm = CS[996 + n], vv = CS[1008 + n];
      float sc = g / sqrtf(vv + 1e-5f);
      float sh = be - mm * sc;
#pragma unroll
      for (int r = 0; r < 4; ++r) {
        int row = r0 + q * 4 + r;
        int bb2 = row / Nn, nn2 = row - bb2 * Nn;
        size_t oi = ((size_t)bb2 * TOUT + n) * Nn + nn2;
        float ov = (s[r] + bz) * sc + sh;
        if (fl) ((float*)outp)[oi] = ov;
        else    ((ush*)outp)[oi] = f2bu(ov);
      }
    }
  }
}

}  // namespace

extern "C" void kernel_launch(void* const* d_in, const int* in_sizes, int n_in,
                              void* d_out, int out_size, void* d_ws, size_t ws_size,
                              hipStream_t stream) {
  float* f = (float*)d_ws;
  int* flag = (int*)d_ws;                 // f[0..15]
  float* CS  = f + 16;                    // 1020 small params (f32)
  float* sd  = f + 1040;                  // 12288
  ush* U = (ush*)(f + 13328);
  ush* phi16 = U;                         // 12288*16
  ush* plo16 = U + 196608;
  ush* lhi16 = U + 393216;
  ush* llo16 = U + 589824;
  ush* Xc    = U + 786432;                // 8*16*1536
  ush* Wf    = U + 983040;                // 199680

  SmallTab st;
  {
    const int idxs[16] = {1, 2, 4, 6, 8, 10, 11, 12, 13, 15, 17, 19, 21, 22, 23, 24};
    const int ns[16]   = {64, 64, 128, 128, 64, 64, 64, 64, 64, 128, 128, 12, 12, 12, 12, 12};
    int off = 0;
    for (int i = 0; i < 16; ++i) {
      st.src[i] = d_in[idxs[i]]; st.n[i] = ns[i]; st.off[i] = off; off += ns[i];
    }
  }
  RepTab rt;
  {
    const int idxs[8]  = {3, 5, 7, 9, 14, 16, 18, 20};
    const int rNc[8]   = {128, 128, 64, 64, 128, 128, 12, 12};
    const int rNCT[8]  = {8, 8, 4, 4, 8, 8, 1, 1};
    const int rlb[9]   = {0, 12288, 14336, 15360, 21504, 22528, 24576, 24832, 24960};
    for (int i = 0; i < 8; ++i) {
      rt.src[i] = d_in[idxs[i]]; rt.Nc[i] = rNc[i]; rt.NCT[i] = rNCT[i];
    }
    for (int i = 0; i < 9; ++i) rt.lb[i] = rlb[i];
  }

  prep_all<<<291, 256, 0, stream>>>(d_in[0], st, rt, flag, CS, sd,
                                    phi16, plo16, lhi16, llo16, Xc, Wf);
  klmlp<<<768, 512, 0, stream>>>(d_in[0], phi16, plo16, lhi16, llo16,
                                 Xc, sd, CS, Wf, flag, d_out);
}

// Round 6
// 143.273 us; speedup vs baseline: 1.0329x; 1.0329x over previous
//
#include <hip/hip_runtime.h>
#include <hip/hip_bf16.h>

// AdaBiD R12: 2-kernel pipeline. MI355X gfx950.  (R10 base + latency fixes)
// B=8, T=12, N=1536, H=64, TH=768, HID2=128, T_OUT=12.
//  K1 prep_all (R10 verbatim): [0,192) softmax 4 thr/row, [192,290) repack,
//               290 smalls + flag.
//  K2 klmlp: fused KL + 6-layer MLP per 16-row tile, 256 thr / 4 waves
//               (R11's 512-thr variant regressed: lb(512,4)->2 blocks/CU ->
//               1.5 dispatch rounds; reverted).
//               R12 deltas: (a) jp loop unroll 2 (next-tile loads hide the
//               LDS mask roundtrip), (b) even/odd accumulator splits on the
//               24/28-long MFMA chains (L1e, L3e eproj), (c) LDS 47.6->38KB:
//               red/red2 overlay wave-private T slabs, L3d reduce overlays zf.

namespace {

constexpr int Nn = 1536, TOUT = 12;

typedef __attribute__((ext_vector_type(8))) short bf8;
typedef __attribute__((ext_vector_type(4))) float f4;
typedef unsigned short ush;

__device__ __forceinline__ float b2f(__hip_bfloat16 v) { return __bfloat162float(v); }
__device__ __forceinline__ ush f2bu(float f) {
  union { __hip_bfloat16 h; ush u; } c; c.h = __float2bfloat16(f); return c.u;
}
__device__ __forceinline__ float bu2f(ush u) {
  union { unsigned int i; float f; } c; c.i = ((unsigned)u) << 16; return c.f;
}
__device__ __forceinline__ float ldraw(const void* p, size_t i, int fl) {
  return fl ? ((const float*)p)[i] : b2f(((const __hip_bfloat16*)p)[i]);
}

// block-local dtype sniff: bf16 N(0,1) never has exp-field >= 140; f32 read
// as ushorts has ~45% of low-halves >= 140.  4096 samples.
__device__ __forceinline__ int detect_fl(const void* x, int tid) {
  __shared__ int cnt;
  if (tid == 0) cnt = 0;
  __syncthreads();
  const ush* u = (const ush*)x;
  int c = 0;
#pragma unroll
  for (int s = 0; s < 16; ++s) {
    ush v = u[tid + s * 256];
    if (((v >> 7) & 0xFF) >= 140) c++;
  }
  atomicAdd(&cnt, c);
  __syncthreads();
  return (cnt > 64) ? 1 : 0;
}

struct SmallTab { const void* src[16]; int n[16]; int off[16]; };
struct RepTab { const void* src[8]; int Nc[8]; int NCT[8]; int lb[9]; };

// ---------------- K1: prep + repack + smalls ---------------------------------
__global__ __launch_bounds__(256) void prep_all(
    const void* __restrict__ xraw, SmallTab st, RepTab rt,
    int* __restrict__ flag, float* __restrict__ CS,
    float* __restrict__ sd,
    ush* __restrict__ phi16, ush* __restrict__ plo16,
    ush* __restrict__ lhi16, ush* __restrict__ llo16,
    ush* __restrict__ Xc, ush* __restrict__ Wf) {
  __shared__ float lvs[64][12];
  int tid = threadIdx.x;
  int fl = detect_fl(xraw, tid);
  int blk = blockIdx.x;

  if (blk < 192) {
    // ---- prep role: 64 rows/block, 4 threads per row ----
    int rl = tid >> 2, sub = tid & 3;
    int row = blk * 64 + rl;
    int b = row / Nn, nn = row - b * Nn;   // 24 blocks/batch, no straddle
    float xv[12];
#pragma unroll
    for (int t = 0; t < 12; ++t)
      xv[t] = ldraw(xraw, (size_t)(b * 12 + t) * Nn + nn, fl);
    // redundant per-sub, bit-identical sequential order
    float mx = xv[0];
#pragma unroll
    for (int t = 1; t < 12; ++t) mx = fmaxf(mx, xv[t]);
    float e[12], Z = 0.f;
#pragma unroll
    for (int t = 0; t < 12; ++t) { e[t] = expf(xv[t] - mx); Z += e[t]; }
    float invZ = 1.f / Z;
    // each sub owns t = sub*3 .. sub*3+2: log + splits + stores
#pragma unroll
    for (int u = 0; u < 3; ++u) {
      int t = sub * 3 + u;
      float pv = e[t] * invZ;
      float lv = logf(pv + 1e-10f);
      lvs[rl][t] = lv;
      ush phv = f2bu(pv);  float plv = pv - bu2f(phv);
      ush lhv = f2bu(lv);  float llv = lv - bu2f(lhv);
      phi16[(size_t)row * 16 + t] = phv;
      plo16[(size_t)row * 16 + t] = f2bu(plv);
      lhi16[(size_t)row * 16 + t] = lhv;
      llo16[(size_t)row * 16 + t] = f2bu(llv);
      Xc[((size_t)(b * 16 + t)) * Nn + nn] = f2bu(xv[t]);
    }
    {  // pads: t = 12+sub for all arrays; Xc ones col at t=12
      int t = 12 + sub;
      phi16[(size_t)row * 16 + t] = 0;
      plo16[(size_t)row * 16 + t] = 0;
      lhi16[(size_t)row * 16 + t] = 0;
      llo16[(size_t)row * 16 + t] = 0;
      Xc[((size_t)(b * 16 + t)) * Nn + nn] = (sub == 0) ? (ush)0x3F80 : (ush)0;
    }
    __syncthreads();
    if (sub == 0) {
      float sacc = 0.f;
#pragma unroll
      for (int t = 0; t < 12; ++t)
        sacc = fmaf(e[t] * invZ, lvs[rl][t], sacc);
      sd[row] = sacc;
    }
  } else if (blk < 290) {
    // ---- repack role: weights -> MFMA B-frag order ----
    int idx = (blk - 192) * 256 + tid;
    if (idx >= rt.lb[8]) return;
    int mi = 0;
#pragma unroll
    for (int i = 1; i < 8; ++i) if (idx >= rt.lb[i]) mi = i;
    int li = idx - rt.lb[mi];
    int NCT = rt.NCT[mi], Nc = rt.Nc[mi];
    int per = NCT * 64;
    int c0 = li / per, rem = li - c0 * per;
    int ct = rem >> 6, l = rem & 63;
    int q = l >> 4, m = l & 15;
    int col = ct * 16 + m;
    ush* d = Wf + (size_t)idx * 8;
#pragma unroll
    for (int j = 0; j < 8; ++j) {
      int k = c0 * 32 + q * 8 + j;
      d[j] = (col < Nc) ? f2bu(ldraw(rt.src[mi], (size_t)k * Nc + col, fl)) : 0;
    }
  } else {
    // ---- smalls role: canonicalize biases/BN params to f32 + publish flag ----
    for (int i = 0; i < 16; ++i)
      for (int e = tid; e < st.n[i]; e += 256)
        CS[st.off[i] + e] = ldraw(st.src[i], e, fl);
    if (tid == 0) flag[0] = fl;
  }
}

// ---------------- K2: fused KL + MLP per 16-row tile -------------------------
__global__ __launch_bounds__(256, 3) void klmlp(
    const void* __restrict__ xraw,
    const ush* __restrict__ phi16, const ush* __restrict__ plo16,
    const ush* __restrict__ lhi16, const ush* __restrict__ llo16,
    const ush* __restrict__ Xc, const float* __restrict__ sd,
    const float* __restrict__ CS, const ush* __restrict__ Wf,
    const int* __restrict__ flag, void* __restrict__ outp) {
  __shared__ float xs[16][12], ccs[16][12];
  __shared__ float sfs[16][16], sbs[16][16];
  __shared__ float ws1[64], ws2[64];
  __shared__ ush hf[2048], hg[2048], xf[1024];
  // One 24KB slab, time-multiplexed:
  //  Phase B: pw[w].T1/T2 = wave-private mask staging; at the end of Phase B
  //           each wave overwrites its own slab with accF/accB (pr overlay;
  //           written only after that wave's last T read).
  //  Phase C: zf = z A-frag cache (filled after the reduction consumed pr);
  //           r3 (overlay of zf, dead after L3e) = L3d K-split reduce buffer.
  __shared__ union {
    struct { ush T1[512]; ush T2[512]; } pw[4];
    struct { f4 rF[64]; f4 rB[64]; } pr[4];
    ush zf[12288];
    f4 r3[256];
  } u;

  int tid = threadIdx.x, w = tid >> 6, l = tid & 63, q = l >> 4, n = l & 15;
  int bi = blockIdx.x;
  int r0 = bi * 16;
  int b = bi / 96;            // 96 blocks per batch (1536/16)
  int rowb = b * Nn;
  int fl = flag[0];

  // xs staging overlaps phase B (independent loads)
  if (tid < 192) {
    int rr = tid / 12, tt = tid - rr * 12;
    xs[rr][tt] = ldraw(xraw, (size_t)(b * 12 + tt) * Nn + (r0 - rowb + rr), fl);
  }

  // ================= Phase B: KL + aggregation, 4 waves split j =============
  {
    bf8 z8 = {0, 0, 0, 0, 0, 0, 0, 0};
    // A-frags straight from the hi/lo row arrays: k<16 -> hi, k>=16 -> lo
    bf8 aP = (q < 2)
        ? *(const bf8*)(phi16 + ((size_t)(r0 + n)) * 16 + q * 8)
        : *(const bf8*)(plo16 + ((size_t)(r0 + n)) * 16 + (q - 2) * 8);
    bf8 aL = (q < 2)
        ? *(const bf8*)(lhi16 + ((size_t)(r0 + n)) * 16 + q * 8)
        : *(const bf8*)(llo16 + ((size_t)(r0 + n)) * 16 + (q - 2) * 8);
    bf8 aPh = (q < 2) ? aP : z8;
    bf8 aLh = (q < 2) ? aL : z8;
    float selfI[4];
#pragma unroll
    for (int r = 0; r < 4; ++r) selfI[r] = sd[r0 + q * 4 + r];

    f4 accF = {0.f, 0.f, 0.f, 0.f}, accB = {0.f, 0.f, 0.f, 0.f};

#pragma unroll 2
    for (int jp = 0; jp < 12; ++jp) {
      int jl = w * 384 + jp * 32;
#pragma unroll
      for (int hh = 0; hh < 2; ++hh) {
        int jh = jl + hh * 16;
        size_t bb = ((size_t)(rowb + jh + n)) * 16 + (q & 1) * 8;
        bf8 bLh = *(const bf8*)(lhi16 + bb);
        bf8 bLo = *(const bf8*)(llo16 + bb);
        bf8 bPh = *(const bf8*)(phi16 + bb);
        bf8 bPo = *(const bf8*)(plo16 + bb);
        float selfJ = sd[rowb + jh + n];

        f4 s1 = {0.f, 0.f, 0.f, 0.f}, s2 = {0.f, 0.f, 0.f, 0.f};
        s1 = __builtin_amdgcn_mfma_f32_16x16x32_bf16(aP, bLh, s1, 0, 0, 0);
        s1 = __builtin_amdgcn_mfma_f32_16x16x32_bf16(aPh, bLo, s1, 0, 0, 0);
        s2 = __builtin_amdgcn_mfma_f32_16x16x32_bf16(aL, bPh, s2, 0, 0, 0);
        s2 = __builtin_amdgcn_mfma_f32_16x16x32_bf16(aLh, bPo, s2, 0, 0, 0);

        int qk = n >> 3, kj = n & 7;
#pragma unroll
        for (int r = 0; r < 4; ++r) {
          int pos = hh * 256 + (qk * 16 + q * 4 + r) * 8 + kj;
          u.pw[w].T1[pos] = (selfI[r] - s1[r] < 0.5f) ? (ush)0x3F80 : (ush)0;
          u.pw[w].T2[pos] = (selfJ - s2[r] < 0.5f) ? (ush)0x3F80 : (ush)0;
        }
      }
      bf8 af1 = *(const bf8*)(&u.pw[w].T1[(size_t)l * 8]);
      bf8 af2 = *(const bf8*)(&u.pw[w].T2[(size_t)l * 8]);
      bf8 xfr = *(const bf8*)(Xc + ((size_t)(b * 16 + n)) * Nn + jl + q * 8);
      accF = __builtin_amdgcn_mfma_f32_16x16x32_bf16(af1, xfr, accF, 0, 0, 0);
      accB = __builtin_amdgcn_mfma_f32_16x16x32_bf16(af2, xfr, accB, 0, 0, 0);
    }
    // overlay own slab (all T reads of this wave are done)
    u.pr[w].rF[l] = accF;
    u.pr[w].rB[l] = accB;
  }
  __syncthreads();

  // j-split reduction -> sfs/sbs; waves 2,3 stage W1/W2 meanwhile
  if (w == 0) {
    f4 s = u.pr[0].rF[l] + u.pr[1].rF[l] + u.pr[2].rF[l] + u.pr[3].rF[l];
#pragma unroll
    for (int r = 0; r < 4; ++r) sfs[q * 4 + r][n] = s[r];
  } else if (w == 1) {
    f4 s = u.pr[0].rB[l] + u.pr[1].rB[l] + u.pr[2].rB[l] + u.pr[3].rB[l];
#pragma unroll
    for (int r = 0; r < 4; ++r) sbs[q * 4 + r][n] = s[r];
  } else if (w == 2) {
    ws1[l] = CS[l];
  } else {
    ws2[l] = CS[64 + l];
  }
  __syncthreads();
  if (tid < 192) {
    int rr = tid / 12, tt = tid - rr * 12;
    float irs = 1.f / fmaxf(sfs[rr][12], 1e-6f);
    float ics = 1.f / fmaxf(sbs[rr][12], 1e-6f);
    ccs[rr][tt] = 3.0f * (0.3f * sfs[rr][tt] * irs + 0.7f * sbs[rr][tt] * ics);
  }
  __syncthreads();

  // ================= Phase C: fused MLP ====================================
  // z A-frag regen: row = r0+n, k = c0*32 + q*8 + j
  auto zregen = [&](int c0) -> bf8 {
    int t = c0 >> 1, h0 = (c0 & 1) * 32 + q * 8;
    float xv = xs[n][t], cv = ccs[n][t];
    union { bf8 v; ush uu[8]; } au;
#pragma unroll
    for (int j = 0; j < 8; ++j)
      au.uu[j] = f2bu(fmaxf(fmaf(xv, ws1[h0 + j], cv * ws2[h0 + j]), 0.f));
    return au.v;
  };
  auto fpos = [&](int ct, int r) -> int {
    return ((ct >> 1) * 64 + ((ct & 1) * 2 + (n >> 3)) * 16 + q * 4 + r) * 8 + (n & 7);
  };

  // fill the z-frag cache (overwrites pw/pr; reduction done): wave w owns 6
#pragma unroll
  for (int u6 = 0; u6 < 6; ++u6) {
    int c0 = w * 6 + u6;
    bf8 v = zregen(c0);
    *(bf8*)(&u.zf[((size_t)c0 * 64 + l) * 8]) = v;
  }
  __syncthreads();

  // --- L1e: h1 = relu(z @ ew1 + b1), N=128, wave does ct = 2w, 2w+1 --------
  // even/odd c0 accumulator split: 4 independent MFMA chains
  {
    f4 a0e = {0.f, 0.f, 0.f, 0.f}, a0o = {0.f, 0.f, 0.f, 0.f};
    f4 a1e = {0.f, 0.f, 0.f, 0.f}, a1o = {0.f, 0.f, 0.f, 0.f};
    for (int c0 = 0; c0 < 24; c0 += 2) {
      bf8 ae = *(const bf8*)(&u.zf[((size_t)c0 * 64 + l) * 8]);
      bf8 ao = *(const bf8*)(&u.zf[((size_t)(c0 + 1) * 64 + l) * 8]);
      const ush* wbe = Wf + ((size_t)(c0 * 8 + 2 * w) * 64 + l) * 8;
      const ush* wbo = Wf + ((size_t)((c0 + 1) * 8 + 2 * w) * 64 + l) * 8;
      a0e = __builtin_amdgcn_mfma_f32_16x16x32_bf16(ae, *(const bf8*)wbe, a0e, 0, 0, 0);
      a1e = __builtin_amdgcn_mfma_f32_16x16x32_bf16(ae, *(const bf8*)(wbe + 512), a1e, 0, 0, 0);
      a0o = __builtin_amdgcn_mfma_f32_16x16x32_bf16(ao, *(const bf8*)wbo, a0o, 0, 0, 0);
      a1o = __builtin_amdgcn_mfma_f32_16x16x32_bf16(ao, *(const bf8*)(wbo + 512), a1o, 0, 0, 0);
    }
    f4 a0 = a0e + a0o, a1 = a1e + a1o;
#pragma unroll
    for (int u2 = 0; u2 < 2; ++u2) {
      int ct = 2 * w + u2;
      f4 acc = u2 ? a1 : a0;
      float bz = CS[128 + ct * 16 + n];
#pragma unroll
      for (int r = 0; r < 4; ++r)
        hf[fpos(ct, r)] = f2bu(fmaxf(acc[r] + bz, 0.f));
    }
  }
  __syncthreads();

  // --- L2e: h2 = relu(h1 @ ew2 + b2), K=128 --------------------------------
  {
    f4 a0 = {0.f, 0.f, 0.f, 0.f}, a1 = {0.f, 0.f, 0.f, 0.f};
    for (int c0 = 0; c0 < 4; ++c0) {
      bf8 a = *(const bf8*)(&hf[(size_t)(c0 * 64 + l) * 8]);
      const ush* wb = Wf + 98304 + ((size_t)(c0 * 8 + 2 * w) * 64 + l) * 8;
      bf8 b0 = *(const bf8*)wb;
      bf8 b1 = *(const bf8*)(wb + 512);
      a0 = __builtin_amdgcn_mfma_f32_16x16x32_bf16(a, b0, a0, 0, 0, 0);
      a1 = __builtin_amdgcn_mfma_f32_16x16x32_bf16(a, b1, a1, 0, 0, 0);
    }
    __syncthreads();   // hf reads complete before later rewrite
#pragma unroll
    for (int u2 = 0; u2 < 2; ++u2) {
      int ct = 2 * w + u2;
      f4 acc = u2 ? a1 : a0;
      float bz = CS[256 + ct * 16 + n];
#pragma unroll
      for (int r = 0; r < 4; ++r)
        hg[fpos(ct, r)] = f2bu(fmaxf(acc[r] + bz, 0.f));
    }
  }
  __syncthreads();

  // --- L3e: xe = BN(h2 @ ew3 + b3 + z @ eproj), N=64, wave does ct = w -----
  // eproj 24-chain split into two independent 12-chains
  {
    f4 a3 = {0.f, 0.f, 0.f, 0.f};
    for (int c0 = 0; c0 < 4; ++c0) {
      bf8 a = *(const bf8*)(&hg[(size_t)(c0 * 64 + l) * 8]);
      bf8 bb = *(const bf8*)(Wf + 114688 + ((size_t)(c0 * 4 + w) * 64 + l) * 8);
      a3 = __builtin_amdgcn_mfma_f32_16x16x32_bf16(a, bb, a3, 0, 0, 0);
    }
    f4 e0 = {0.f, 0.f, 0.f, 0.f}, e1 = {0.f, 0.f, 0.f, 0.f};
    for (int c0 = 0; c0 < 12; ++c0) {
      bf8 aa = *(const bf8*)(&u.zf[((size_t)c0 * 64 + l) * 8]);
      bf8 ab = *(const bf8*)(&u.zf[((size_t)(c0 + 12) * 64 + l) * 8]);
      bf8 ba = *(const bf8*)(Wf + 122880 + ((size_t)(c0 * 4 + w) * 64 + l) * 8);
      bf8 bbq = *(const bf8*)(Wf + 122880 + ((size_t)((c0 + 12) * 4 + w) * 64 + l) * 8);
      e0 = __builtin_amdgcn_mfma_f32_16x16x32_bf16(aa, ba, e0, 0, 0, 0);
      e1 = __builtin_amdgcn_mfma_f32_16x16x32_bf16(ab, bbq, e1, 0, 0, 0);
    }
    a3 = a3 + e0 + e1;
    int col = w * 16 + n;
    float g = CS[448 + col], be = CS[512 + col], mm = CS[576 + col], vv = CS[640 + col];
    float sc = g / sqrtf(vv + 1e-5f);
    float sh = be - mm * sc;
    float bz = CS[384 + col];
#pragma unroll
    for (int r = 0; r < 4; ++r)
      xf[fpos(w, r)] = f2bu((a3[r] + bz) * sc + sh);
  }
  __syncthreads();

  // --- L1d: g1 = relu(xe @ dw1 + b1), K=64, N=128 --------------------------
  {
    f4 a0 = {0.f, 0.f, 0.f, 0.f}, a1 = {0.f, 0.f, 0.f, 0.f};
    for (int c0 = 0; c0 < 2; ++c0) {
      bf8 a = *(const bf8*)(&xf[(size_t)(c0 * 64 + l) * 8]);
      const ush* wb = Wf + 172032 + ((size_t)(c0 * 8 + 2 * w) * 64 + l) * 8;
      bf8 b0 = *(const bf8*)wb;
      bf8 b1 = *(const bf8*)(wb + 512);
      a0 = __builtin_amdgcn_mfma_f32_16x16x32_bf16(a, b0, a0, 0, 0, 0);
      a1 = __builtin_amdgcn_mfma_f32_16x16x32_bf16(a, b1, a1, 0, 0, 0);
    }
    __syncthreads();   // hf rewrite fence
#pragma unroll
    for (int u2 = 0; u2 < 2; ++u2) {
      int ct = 2 * w + u2;
      f4 acc = u2 ? a1 : a0;
      float bz = CS[704 + ct * 16 + n];
#pragma unroll
      for (int r = 0; r < 4; ++r)
        hf[fpos(ct, r)] = f2bu(fmaxf(acc[r] + bz, 0.f));
    }
  }
  __syncthreads();

  // --- L2d: g2 = relu(g1 @ dw2 + b2), K=128 --------------------------------
  {
    f4 a0 = {0.f, 0.f, 0.f, 0.f}, a1 = {0.f, 0.f, 0.f, 0.f};
    for (int c0 = 0; c0 < 4; ++c0) {
      bf8 a = *(const bf8*)(&hf[(size_t)(c0 * 64 + l) * 8]);
      const ush* wb = Wf + 180224 + ((size_t)(c0 * 8 + 2 * w) * 64 + l) * 8;
      bf8 b0 = *(const bf8*)wb;
      bf8 b1 = *(const bf8*)(wb + 512);
      a0 = __builtin_amdgcn_mfma_f32_16x16x32_bf16(a, b0, a0, 0, 0, 0);
      a1 = __builtin_amdgcn_mfma_f32_16x16x32_bf16(a, b1, a1, 0, 0, 0);
    }
    __syncthreads();   // hg rewrite fence
#pragma unroll
    for (int u2 = 0; u2 < 2; ++u2) {
      int ct = 2 * w + u2;
      f4 acc = u2 ? a1 : a0;
      float bz = CS[832 + ct * 16 + n];
#pragma unroll
      for (int r = 0; r < 4; ++r)
        hg[fpos(ct, r)] = f2bu(fmaxf(acc[r] + bz, 0.f));
    }
  }
  __syncthreads();

  // --- L3d: out = BN(g2 @ dw3 + b3 + xe @ dproj), N=12; K-split 4 waves ----
  // reduce buffer r3 overlays zf (zf dead after L3e; barrier since)
  {
    f4 ao = {0.f, 0.f, 0.f, 0.f};
    {  // dw3 chunk c0 = w  (K=128 -> 4 chunks)
      bf8 a = *(const bf8*)(&hg[(size_t)(w * 64 + l) * 8]);
      bf8 bb = *(const bf8*)(Wf + 196608 + ((size_t)w * 64 + l) * 8);
      ao = __builtin_amdgcn_mfma_f32_16x16x32_bf16(a, bb, ao, 0, 0, 0);
    }
    if (w < 2) {  // dproj chunk c0 = w  (K=64 -> 2 chunks)
      bf8 a = *(const bf8*)(&xf[(size_t)(w * 64 + l) * 8]);
      bf8 bb = *(const bf8*)(Wf + 198656 + ((size_t)w * 64 + l) * 8);
      ao = __builtin_amdgcn_mfma_f32_16x16x32_bf16(a, bb, ao, 0, 0, 0);
    }
    u.r3[w * 64 + l] = ao;
  }
  __syncthreads();
  if (w == 0) {
    f4 s = u.r3[l] + u.r3[64 + l] + u.r3[128 + l] + u.r3[192 + l];
    if (n < 12) {
      float bz = CS[960 + n];
      float g = CS[972 + n], be = CS[984 + n], mm = CS[996 + n], vv = CS[1008 + n];
      float sc = g / sqrtf(vv + 1e-5f);
      float sh = be - mm * sc;
#pragma unroll
      for (int r = 0; r < 4; ++r) {
        int row = r0 + q * 4 + r;
        int bb2 = row / Nn, nn2 = row - bb2 * Nn;
        size_t oi = ((size_t)bb2 * TOUT + n) * Nn + nn2;
        float ov = (s[r] + bz) * sc + sh;
        if (fl) ((float*)outp)[oi] = ov;
        else    ((ush*)outp)[oi] = f2bu(ov);
      }
    }
  }
}

}  // namespace

extern "C" void kernel_launch(void* const* d_in, const int* in_sizes, int n_in,
                              void* d_out, int out_size, void* d_ws, size_t ws_size,
                              hipStream_t stream) {
  float* f = (float*)d_ws;
  int* flag = (int*)d_ws;                 // f[0..15]
  float* CS  = f + 16;                    // 1020 small params (f32)
  float* sd  = f + 1040;                  // 12288
  ush* U = (ush*)(f + 13328);
  ush* phi16 = U;                         // 12288*16
  ush* plo16 = U + 196608;
  ush* lhi16 = U + 393216;
  ush* llo16 = U + 589824;
  ush* Xc    = U + 786432;                // 8*16*1536
  ush* Wf    = U + 983040;                // 199680

  SmallTab st;
  {
    const int idxs[16] = {1, 2, 4, 6, 8, 10, 11, 12, 13, 15, 17, 19, 21, 22, 23, 24};
    const int ns[16]   = {64, 64, 128, 128, 64, 64, 64, 64, 64, 128, 128, 12, 12, 12, 12, 12};
    int off = 0;
    for (int i = 0; i < 16; ++i) {
      st.src[i] = d_in[idxs[i]]; st.n[i] = ns[i]; st.off[i] = off; off += ns[i];
    }
  }
  RepTab rt;
  {
    const int idxs[8]  = {3, 5, 7, 9, 14, 16, 18, 20};
    const int rNc[8]   = {128, 128, 64, 64, 128, 128, 12, 12};
    const int rNCT[8]  = {8, 8, 4, 4, 8, 8, 1, 1};
    const int rlb[9]   = {0, 12288, 14336, 15360, 21504, 22528, 24576, 24832, 24960};
    for (int i = 0; i < 8; ++i) {
      rt.src[i] = d_in[idxs[i]]; rt.Nc[i] = rNc[i]; rt.NCT[i] = rNCT[i];
    }
    for (int i = 0; i < 9; ++i) rt.lb[i] = rlb[i];
  }

  prep_all<<<291, 256, 0, stream>>>(d_in[0], st, rt, flag, CS, sd,
                                    phi16, plo16, lhi16, llo16, Xc, Wf);
  klmlp<<<768, 256, 0, stream>>>(d_in[0], phi16, plo16, lhi16, llo16,
                                 Xc, sd, CS, Wf, flag, d_out);
}

// Round 7
// 142.711 us; speedup vs baseline: 1.0369x; 1.0039x over previous
//
#include <hip/hip_runtime.h>
#include <hip/hip_bf16.h>

// AdaBiD R13: 2-kernel pipeline. MI355X gfx950.  (= R10 + MFMA-chain splits)
// B=8, T=12, N=1536, H=64, TH=768, HID2=128, T_OUT=12.
//  K1 prep_all (R10 verbatim): [0,192) softmax 4 thr/row, [192,290) repack,
//               290 smalls + flag.
//  K2 klmlp (R10 base): fused KL + 6-layer MLP per 16-row tile, 256 thr /
//               4 waves, 47.6KB LDS -> 3 blocks/CU (= grid 768 exactly).
//               R13 sole delta vs R10: L1e split into 4 independent MFMA
//               accumulator chains (even/odd c0 x 2 cols) and L3e eproj into
//               2 chains -- halves/quarters the serial MFMA->acc latency
//               chain (~32cyc/MFMA) that 3 waves/SIMD can't fully hide.
//               (R12's jp-unroll-2 regressed: doubled B-frag live ranges vs
//               the lb(256,3) 168-VGPR cap; dropped. R11's 8-wave regressed:
//               2 blocks/CU -> 1.5 dispatch rounds; dropped.)

namespace {

constexpr int Nn = 1536, TOUT = 12;

typedef __attribute__((ext_vector_type(8))) short bf8;
typedef __attribute__((ext_vector_type(4))) float f4;
typedef unsigned short ush;

__device__ __forceinline__ float b2f(__hip_bfloat16 v) { return __bfloat162float(v); }
__device__ __forceinline__ ush f2bu(float f) {
  union { __hip_bfloat16 h; ush u; } c; c.h = __float2bfloat16(f); return c.u;
}
__device__ __forceinline__ float bu2f(ush u) {
  union { unsigned int i; float f; } c; c.i = ((unsigned)u) << 16; return c.f;
}
__device__ __forceinline__ float ldraw(const void* p, size_t i, int fl) {
  return fl ? ((const float*)p)[i] : b2f(((const __hip_bfloat16*)p)[i]);
}

// block-local dtype sniff: bf16 N(0,1) never has exp-field >= 140; f32 read
// as ushorts has ~45% of low-halves >= 140.  4096 samples.
__device__ __forceinline__ int detect_fl(const void* x, int tid) {
  __shared__ int cnt;
  if (tid == 0) cnt = 0;
  __syncthreads();
  const ush* u = (const ush*)x;
  int c = 0;
#pragma unroll
  for (int s = 0; s < 16; ++s) {
    ush v = u[tid + s * 256];
    if (((v >> 7) & 0xFF) >= 140) c++;
  }
  atomicAdd(&cnt, c);
  __syncthreads();
  return (cnt > 64) ? 1 : 0;
}

struct SmallTab { const void* src[16]; int n[16]; int off[16]; };
struct RepTab { const void* src[8]; int Nc[8]; int NCT[8]; int lb[9]; };

// ---------------- K1: prep + repack + smalls ---------------------------------
__global__ __launch_bounds__(256) void prep_all(
    const void* __restrict__ xraw, SmallTab st, RepTab rt,
    int* __restrict__ flag, float* __restrict__ CS,
    float* __restrict__ sd,
    ush* __restrict__ phi16, ush* __restrict__ plo16,
    ush* __restrict__ lhi16, ush* __restrict__ llo16,
    ush* __restrict__ Xc, ush* __restrict__ Wf) {
  __shared__ float lvs[64][12];
  int tid = threadIdx.x;
  int fl = detect_fl(xraw, tid);
  int blk = blockIdx.x;

  if (blk < 192) {
    // ---- prep role: 64 rows/block, 4 threads per row ----
    int rl = tid >> 2, sub = tid & 3;
    int row = blk * 64 + rl;
    int b = row / Nn, nn = row - b * Nn;   // 24 blocks/batch, no straddle
    float xv[12];
#pragma unroll
    for (int t = 0; t < 12; ++t)
      xv[t] = ldraw(xraw, (size_t)(b * 12 + t) * Nn + nn, fl);
    // redundant per-sub, bit-identical sequential order
    float mx = xv[0];
#pragma unroll
    for (int t = 1; t < 12; ++t) mx = fmaxf(mx, xv[t]);
    float e[12], Z = 0.f;
#pragma unroll
    for (int t = 0; t < 12; ++t) { e[t] = expf(xv[t] - mx); Z += e[t]; }
    float invZ = 1.f / Z;
    // each sub owns t = sub*3 .. sub*3+2: log + splits + stores
#pragma unroll
    for (int u = 0; u < 3; ++u) {
      int t = sub * 3 + u;
      float pv = e[t] * invZ;
      float lv = logf(pv + 1e-10f);
      lvs[rl][t] = lv;
      ush phv = f2bu(pv);  float plv = pv - bu2f(phv);
      ush lhv = f2bu(lv);  float llv = lv - bu2f(lhv);
      phi16[(size_t)row * 16 + t] = phv;
      plo16[(size_t)row * 16 + t] = f2bu(plv);
      lhi16[(size_t)row * 16 + t] = lhv;
      llo16[(size_t)row * 16 + t] = f2bu(llv);
      Xc[((size_t)(b * 16 + t)) * Nn + nn] = f2bu(xv[t]);
    }
    {  // pads: t = 12+sub for all arrays; Xc ones col at t=12
      int t = 12 + sub;
      phi16[(size_t)row * 16 + t] = 0;
      plo16[(size_t)row * 16 + t] = 0;
      lhi16[(size_t)row * 16 + t] = 0;
      llo16[(size_t)row * 16 + t] = 0;
      Xc[((size_t)(b * 16 + t)) * Nn + nn] = (sub == 0) ? (ush)0x3F80 : (ush)0;
    }
    __syncthreads();
    if (sub == 0) {
      float sacc = 0.f;
#pragma unroll
      for (int t = 0; t < 12; ++t)
        sacc = fmaf(e[t] * invZ, lvs[rl][t], sacc);
      sd[row] = sacc;
    }
  } else if (blk < 290) {
    // ---- repack role: weights -> MFMA B-frag order ----
    int idx = (blk - 192) * 256 + tid;
    if (idx >= rt.lb[8]) return;
    int mi = 0;
#pragma unroll
    for (int i = 1; i < 8; ++i) if (idx >= rt.lb[i]) mi = i;
    int li = idx - rt.lb[mi];
    int NCT = rt.NCT[mi], Nc = rt.Nc[mi];
    int per = NCT * 64;
    int c0 = li / per, rem = li - c0 * per;
    int ct = rem >> 6, l = rem & 63;
    int q = l >> 4, m = l & 15;
    int col = ct * 16 + m;
    ush* d = Wf + (size_t)idx * 8;
#pragma unroll
    for (int j = 0; j < 8; ++j) {
      int k = c0 * 32 + q * 8 + j;
      d[j] = (col < Nc) ? f2bu(ldraw(rt.src[mi], (size_t)k * Nc + col, fl)) : 0;
    }
  } else {
    // ---- smalls role: canonicalize biases/BN params to f32 + publish flag ----
    for (int i = 0; i < 16; ++i)
      for (int e = tid; e < st.n[i]; e += 256)
        CS[st.off[i] + e] = ldraw(st.src[i], e, fl);
    if (tid == 0) flag[0] = fl;
  }
}

// ---------------- K2: fused KL + MLP per 16-row tile -------------------------
__global__ __launch_bounds__(256, 3) void klmlp(
    const void* __restrict__ xraw,
    const ush* __restrict__ phi16, const ush* __restrict__ plo16,
    const ush* __restrict__ lhi16, const ush* __restrict__ llo16,
    const ush* __restrict__ Xc, const float* __restrict__ sd,
    const float* __restrict__ CS, const ush* __restrict__ Wf,
    const int* __restrict__ flag, void* __restrict__ outp) {
  __shared__ float xs[16][12], ccs[16][12];
  __shared__ float sfs[16][16], sbs[16][16];
  __shared__ float ws1[64], ws2[64];
  __shared__ ush hf[2048], hg[2048], xf[1024];
  __shared__ f4 red[4][64], red2[4][64];
  __shared__ union { ush T[2][4][512]; ush zf[12288]; } u;   // 24 KB alias

  int tid = threadIdx.x, w = tid >> 6, l = tid & 63, q = l >> 4, n = l & 15;
  int bi = blockIdx.x;
  int r0 = bi * 16;
  int b = bi / 96;            // 96 blocks per batch (1536/16)
  int rowb = b * Nn;
  int fl = flag[0];

  // xs staging overlaps phase B (independent loads)
  if (tid < 192) {
    int rr = tid / 12, tt = tid - rr * 12;
    xs[rr][tt] = ldraw(xraw, (size_t)(b * 12 + tt) * Nn + (r0 - rowb + rr), fl);
  }

  // ================= Phase B: KL + aggregation, 4 waves split j =============
  {
    bf8 z8 = {0, 0, 0, 0, 0, 0, 0, 0};
    // A-frags straight from the hi/lo row arrays: k<16 -> hi, k>=16 -> lo
    bf8 aP = (q < 2)
        ? *(const bf8*)(phi16 + ((size_t)(r0 + n)) * 16 + q * 8)
        : *(const bf8*)(plo16 + ((size_t)(r0 + n)) * 16 + (q - 2) * 8);
    bf8 aL = (q < 2)
        ? *(const bf8*)(lhi16 + ((size_t)(r0 + n)) * 16 + q * 8)
        : *(const bf8*)(llo16 + ((size_t)(r0 + n)) * 16 + (q - 2) * 8);
    bf8 aPh = (q < 2) ? aP : z8;
    bf8 aLh = (q < 2) ? aL : z8;
    float selfI[4];
#pragma unroll
    for (int r = 0; r < 4; ++r) selfI[r] = sd[r0 + q * 4 + r];

    f4 accF = {0.f, 0.f, 0.f, 0.f}, accB = {0.f, 0.f, 0.f, 0.f};

    for (int jp = 0; jp < 12; ++jp) {
      int jl = w * 384 + jp * 32;
#pragma unroll
      for (int hh = 0; hh < 2; ++hh) {
        int jh = jl + hh * 16;
        size_t bb = ((size_t)(rowb + jh + n)) * 16 + (q & 1) * 8;
        bf8 bLh = *(const bf8*)(lhi16 + bb);
        bf8 bLo = *(const bf8*)(llo16 + bb);
        bf8 bPh = *(const bf8*)(phi16 + bb);
        bf8 bPo = *(const bf8*)(plo16 + bb);
        float selfJ = sd[rowb + jh + n];

        f4 s1 = {0.f, 0.f, 0.f, 0.f}, s2 = {0.f, 0.f, 0.f, 0.f};
        s1 = __builtin_amdgcn_mfma_f32_16x16x32_bf16(aP, bLh, s1, 0, 0, 0);
        s1 = __builtin_amdgcn_mfma_f32_16x16x32_bf16(aPh, bLo, s1, 0, 0, 0);
        s2 = __builtin_amdgcn_mfma_f32_16x16x32_bf16(aL, bPh, s2, 0, 0, 0);
        s2 = __builtin_amdgcn_mfma_f32_16x16x32_bf16(aLh, bPo, s2, 0, 0, 0);

        int qk = n >> 3, kj = n & 7;
#pragma unroll
        for (int r = 0; r < 4; ++r) {
          int pos = hh * 256 + (qk * 16 + q * 4 + r) * 8 + kj;
          u.T[0][w][pos] = (selfI[r] - s1[r] < 0.5f) ? (ush)0x3F80 : (ush)0;
          u.T[1][w][pos] = (selfJ - s2[r] < 0.5f) ? (ush)0x3F80 : (ush)0;
        }
      }
      bf8 af1 = *(const bf8*)(&u.T[0][w][(size_t)l * 8]);
      bf8 af2 = *(const bf8*)(&u.T[1][w][(size_t)l * 8]);
      bf8 xfr = *(const bf8*)(Xc + ((size_t)(b * 16 + n)) * Nn + jl + q * 8);
      accF = __builtin_amdgcn_mfma_f32_16x16x32_bf16(af1, xfr, accF, 0, 0, 0);
      accB = __builtin_amdgcn_mfma_f32_16x16x32_bf16(af2, xfr, accB, 0, 0, 0);
    }
    red[w][l] = accF;
    red2[w][l] = accB;
  }
  __syncthreads();

  // j-split reduction -> sfs/sbs; waves 2,3 stage W1/W2 meanwhile
  if (w == 0) {
    f4 s = red[0][l] + red[1][l] + red[2][l] + red[3][l];
#pragma unroll
    for (int r = 0; r < 4; ++r) sfs[q * 4 + r][n] = s[r];
  } else if (w == 1) {
    f4 s = red2[0][l] + red2[1][l] + red2[2][l] + red2[3][l];
#pragma unroll
    for (int r = 0; r < 4; ++r) sbs[q * 4 + r][n] = s[r];
  } else if (w == 2) {
    ws1[l] = CS[l];
  } else {
    ws2[l] = CS[64 + l];
  }
  __syncthreads();
  if (tid < 192) {
    int rr = tid / 12, tt = tid - rr * 12;
    float irs = 1.f / fmaxf(sfs[rr][12], 1e-6f);
    float ics = 1.f / fmaxf(sbs[rr][12], 1e-6f);
    ccs[rr][tt] = 3.0f * (0.3f * sfs[rr][tt] * irs + 0.7f * sbs[rr][tt] * ics);
  }
  __syncthreads();

  // ================= Phase C: fused MLP ====================================
  // z A-frag regen: row = r0+n, k = c0*32 + q*8 + j
  auto zregen = [&](int c0) -> bf8 {
    int t = c0 >> 1, h0 = (c0 & 1) * 32 + q * 8;
    float xv = xs[n][t], cv = ccs[n][t];
    union { bf8 v; ush uu[8]; } au;
#pragma unroll
    for (int j = 0; j < 8; ++j)
      au.uu[j] = f2bu(fmaxf(fmaf(xv, ws1[h0 + j], cv * ws2[h0 + j]), 0.f));
    return au.v;
  };
  auto fpos = [&](int ct, int r) -> int {
    return ((ct >> 1) * 64 + ((ct & 1) * 2 + (n >> 3)) * 16 + q * 4 + r) * 8 + (n & 7);
  };

  // fill the z-frag cache (aliases T; all T reads are done): wave w owns 6 c0s
#pragma unroll
  for (int u6 = 0; u6 < 6; ++u6) {
    int c0 = w * 6 + u6;
    bf8 v = zregen(c0);
    *(bf8*)(&u.zf[((size_t)c0 * 64 + l) * 8]) = v;
  }
  __syncthreads();

  // --- L1e: h1 = relu(z @ ew1 + b1), N=128, wave does ct = 2w, 2w+1 --------
  // R13: even/odd c0 accumulator split -> 4 independent MFMA chains
  {
    f4 a0e = {0.f, 0.f, 0.f, 0.f}, a0o = {0.f, 0.f, 0.f, 0.f};
    f4 a1e = {0.f, 0.f, 0.f, 0.f}, a1o = {0.f, 0.f, 0.f, 0.f};
    for (int c0 = 0; c0 < 24; c0 += 2) {
      bf8 ae = *(const bf8*)(&u.zf[((size_t)c0 * 64 + l) * 8]);
      bf8 ao = *(const bf8*)(&u.zf[((size_t)(c0 + 1) * 64 + l) * 8]);
      const ush* wbe = Wf + ((size_t)(c0 * 8 + 2 * w) * 64 + l) * 8;
      const ush* wbo = Wf + ((size_t)((c0 + 1) * 8 + 2 * w) * 64 + l) * 8;
      a0e = __builtin_amdgcn_mfma_f32_16x16x32_bf16(ae, *(const bf8*)wbe, a0e, 0, 0, 0);
      a1e = __builtin_amdgcn_mfma_f32_16x16x32_bf16(ae, *(const bf8*)(wbe + 512), a1e, 0, 0, 0);
      a0o = __builtin_amdgcn_mfma_f32_16x16x32_bf16(ao, *(const bf8*)wbo, a0o, 0, 0, 0);
      a1o = __builtin_amdgcn_mfma_f32_16x16x32_bf16(ao, *(const bf8*)(wbo + 512), a1o, 0, 0, 0);
    }
    f4 a0 = a0e + a0o, a1 = a1e + a1o;
#pragma unroll
    for (int u2 = 0; u2 < 2; ++u2) {
      int ct = 2 * w + u2;
      f4 acc = u2 ? a1 : a0;
      float bz = CS[128 + ct * 16 + n];
#pragma unroll
      for (int r = 0; r < 4; ++r)
        hf[fpos(ct, r)] = f2bu(fmaxf(acc[r] + bz, 0.f));
    }
  }
  __syncthreads();

  // --- L2e: h2 = relu(h1 @ ew2 + b2), K=128 --------------------------------
  {
    f4 a0 = {0.f, 0.f, 0.f, 0.f}, a1 = {0.f, 0.f, 0.f, 0.f};
    for (int c0 = 0; c0 < 4; ++c0) {
      bf8 a = *(const bf8*)(&hf[(size_t)(c0 * 64 + l) * 8]);
      const ush* wb = Wf + 98304 + ((size_t)(c0 * 8 + 2 * w) * 64 + l) * 8;
      bf8 b0 = *(const bf8*)wb;
      bf8 b1 = *(const bf8*)(wb + 512);
      a0 = __builtin_amdgcn_mfma_f32_16x16x32_bf16(a, b0, a0, 0, 0, 0);
      a1 = __builtin_amdgcn_mfma_f32_16x16x32_bf16(a, b1, a1, 0, 0, 0);
    }
    __syncthreads();   // hf reads complete before later rewrite
#pragma unroll
    for (int u2 = 0; u2 < 2; ++u2) {
      int ct = 2 * w + u2;
      f4 acc = u2 ? a1 : a0;
      float bz = CS[256 + ct * 16 + n];
#pragma unroll
      for (int r = 0; r < 4; ++r)
        hg[fpos(ct, r)] = f2bu(fmaxf(acc[r] + bz, 0.f));
    }
  }
  __syncthreads();

  // --- L3e: xe = BN(h2 @ ew3 + b3 + z @ eproj), N=64, wave does ct = w -----
  // R13: eproj 24-chain split into two independent 12-chains
  {
    f4 a3 = {0.f, 0.f, 0.f, 0.f};
    for (int c0 = 0; c0 < 4; ++c0) {
      bf8 a = *(const bf8*)(&hg[(size_t)(c0 * 64 + l) * 8]);
      bf8 bb = *(const bf8*)(Wf + 114688 + ((size_t)(c0 * 4 + w) * 64 + l) * 8);
      a3 = __builtin_amdgcn_mfma_f32_16x16x32_bf16(a, bb, a3, 0, 0, 0);
    }
    f4 e0 = {0.f, 0.f, 0.f, 0.f}, e1 = {0.f, 0.f, 0.f, 0.f};
    for (int c0 = 0; c0 < 12; ++c0) {
      bf8 aa = *(const bf8*)(&u.zf[((size_t)c0 * 64 + l) * 8]);
      bf8 ab = *(const bf8*)(&u.zf[((size_t)(c0 + 12) * 64 + l) * 8]);
      bf8 ba = *(const bf8*)(Wf + 122880 + ((size_t)(c0 * 4 + w) * 64 + l) * 8);
      bf8 bbq = *(const bf8*)(Wf + 122880 + ((size_t)((c0 + 12) * 4 + w) * 64 + l) * 8);
      e0 = __builtin_amdgcn_mfma_f32_16x16x32_bf16(aa, ba, e0, 0, 0, 0);
      e1 = __builtin_amdgcn_mfma_f32_16x16x32_bf16(ab, bbq, e1, 0, 0, 0);
    }
    a3 = a3 + e0 + e1;
    int col = w * 16 + n;
    float g = CS[448 + col], be = CS[512 + col], mm = CS[576 + col], vv = CS[640 + col];
    float sc = g / sqrtf(vv + 1e-5f);
    float sh = be - mm * sc;
    float bz = CS[384 + col];
#pragma unroll
    for (int r = 0; r < 4; ++r)
      xf[fpos(w, r)] = f2bu((a3[r] + bz) * sc + sh);
  }
  __syncthreads();

  // --- L1d: g1 = relu(xe @ dw1 + b1), K=64, N=128 --------------------------
  {
    f4 a0 = {0.f, 0.f, 0.f, 0.f}, a1 = {0.f, 0.f, 0.f, 0.f};
    for (int c0 = 0; c0 < 2; ++c0) {
      bf8 a = *(const bf8*)(&xf[(size_t)(c0 * 64 + l) * 8]);
      const ush* wb = Wf + 172032 + ((size_t)(c0 * 8 + 2 * w) * 64 + l) * 8;
      bf8 b0 = *(const bf8*)wb;
      bf8 b1 = *(const bf8*)(wb + 512);
      a0 = __builtin_amdgcn_mfma_f32_16x16x32_bf16(a, b0, a0, 0, 0, 0);
      a1 = __builtin_amdgcn_mfma_f32_16x16x32_bf16(a, b1, a1, 0, 0, 0);
    }
    __syncthreads();   // hf rewrite fence
#pragma unroll
    for (int u2 = 0; u2 < 2; ++u2) {
      int ct = 2 * w + u2;
      f4 acc = u2 ? a1 : a0;
      float bz = CS[704 + ct * 16 + n];
#pragma unroll
      for (int r = 0; r < 4; ++r)
        hf[fpos(ct, r)] = f2bu(fmaxf(acc[r] + bz, 0.f));
    }
  }
  __syncthreads();

  // --- L2d: g2 = relu(g1 @ dw2 + b2), K=128 --------------------------------
  {
    f4 a0 = {0.f, 0.f, 0.f, 0.f}, a1 = {0.f, 0.f, 0.f, 0.f};
    for (int c0 = 0; c0 < 4; ++c0) {
      bf8 a = *(const bf8*)(&hf[(size_t)(c0 * 64 + l) * 8]);
      const ush* wb = Wf + 180224 + ((size_t)(c0 * 8 + 2 * w) * 64 + l) * 8;
      bf8 b0 = *(const bf8*)wb;
      bf8 b1 = *(const bf8*)(wb + 512);
      a0 = __builtin_amdgcn_mfma_f32_16x16x32_bf16(a, b0, a0, 0, 0, 0);
      a1 = __builtin_amdgcn_mfma_f32_16x16x32_bf16(a, b1, a1, 0, 0, 0);
    }
    __syncthreads();   // hg rewrite fence
#pragma unroll
    for (int u2 = 0; u2 < 2; ++u2) {
      int ct = 2 * w + u2;
      f4 acc = u2 ? a1 : a0;
      float bz = CS[832 + ct * 16 + n];
#pragma unroll
      for (int r = 0; r < 4; ++r)
        hg[fpos(ct, r)] = f2bu(fmaxf(acc[r] + bz, 0.f));
    }
  }
  __syncthreads();

  // --- L3d: out = BN(g2 @ dw3 + b3 + xe @ dproj), N=12; K-split 4 waves ----
  {
    f4 ao = {0.f, 0.f, 0.f, 0.f};
    {  // dw3 chunk c0 = w  (K=128 -> 4 chunks)
      bf8 a = *(const bf8*)(&hg[(size_t)(w * 64 + l) * 8]);
      bf8 bb = *(const bf8*)(Wf + 196608 + ((size_t)w * 64 + l) * 8);
      ao = __builtin_amdgcn_mfma_f32_16x16x32_bf16(a, bb, ao, 0, 0, 0);
    }
    if (w < 2) {  // dproj chunk c0 = w  (K=64 -> 2 chunks)
      bf8 a = *(const bf8*)(&xf[(size_t)(w * 64 + l) * 8]);
      bf8 bb = *(const bf8*)(Wf + 198656 + ((size_t)(w) * 64 + l) * 8);
      ao = __builtin_amdgcn_mfma_f32_16x16x32_bf16(a, bb, ao, 0, 0, 0);
    }
    red[w][l] = ao;
  }
  __syncthreads();
  if (w == 0) {
    f4 s = red[0][l] + red[1][l] + red[2][l] + red[3][l];
    if (n < 12) {
      float bz = CS[960 + n];
      float g = CS[972 + n], be = CS[984 + n], mm = CS[996 + n], vv = CS[1008 + n];
      float sc = g / sqrtf(vv + 1e-5f);
      float sh = be - mm * sc;
#pragma unroll
      for (int r = 0; r < 4; ++r) {
        int row = r0 + q * 4 + r;
        int bb2 = row / Nn, nn2 = row - bb2 * Nn;
        size_t oi = ((size_t)bb2 * TOUT + n) * Nn + nn2;
        float ov = (s[r] + bz) * sc + sh;
        if (fl) ((float*)outp)[oi] = ov;
        else    ((ush*)outp)[oi] = f2bu(ov);
      }
    }
  }
}

}  // namespace

extern "C" void kernel_launch(void* const* d_in, const int* in_sizes, int n_in,
                              void* d_out, int out_size, void* d_ws, size_t ws_size,
                              hipStream_t stream) {
  float* f = (float*)d_ws;
  int* flag = (int*)d_ws;                 // f[0..15]
  float* CS  = f + 16;                    // 1020 small params (f32)
  float* sd  = f + 1040;                  // 12288
  ush* U = (ush*)(f + 13328);
  ush* phi16 = U;                         // 12288*16
  ush* plo16 = U + 196608;
  ush* lhi16 = U + 393216;
  ush* llo16 = U + 589824;
  ush* Xc    = U + 786432;                // 8*16*1536
  ush* Wf    = U + 983040;                // 199680

  SmallTab st;
  {
    const int idxs[16] = {1, 2, 4, 6, 8, 10, 11, 12, 13, 15, 17, 19, 21, 22, 23, 24};
    const int ns[16]   = {64, 64, 128, 128, 64, 64, 64, 64, 64, 128, 128, 12, 12, 12, 12, 12};
    int off = 0;
    for (int i = 0; i < 16; ++i) {
      st.src[i] = d_in[idxs[i]]; st.n[i] = ns[i]; st.off[i] = off; off += ns[i];
    }
  }
  RepTab rt;
  {
    const int idxs[8]  = {3, 5, 7, 9, 14, 16, 18, 20};
    const int rNc[8]   = {128, 128, 64, 64, 128, 128, 12, 12};
    const int rNCT[8]  = {8, 8, 4, 4, 8, 8, 1, 1};
    const int rlb[9]   = {0, 12288, 14336, 15360, 21504, 22528, 24576, 24832, 24960};
    for (int i = 0; i < 8; ++i) {
      rt.src[i] = d_in[idxs[i]]; rt.Nc[i] = rNc[i]; rt.NCT[i] = rNCT[i];
    }
    for (int i = 0; i < 9; ++i) rt.lb[i] = rlb[i];
  }

  prep_all<<<291, 256, 0, stream>>>(d_in[0], st, rt, flag, CS, sd,
                                    phi16, plo16, lhi16, llo16, Xc, Wf);
  klmlp<<<768, 256, 0, stream>>>(d_in[0], phi16, plo16, lhi16, llo16,
                                 Xc, sd, CS, Wf, flag, d_out);
}

// Round 9
// 141.938 us; speedup vs baseline: 1.0426x; 1.0054x over previous
//
#include <hip/hip_runtime.h>
#include <hip/hip_bf16.h>

// AdaBiD R15 (= R10 verbatim, measured best 139.3us; R14 rerun lost to an
// infra failure "container failed twice" -- no dispatch ran). MI355X gfx950.
// B=8, T=12, N=1536, H=64, TH=768, HID2=128, T_OUT=12.
//  K1 prep_all: [0,192) softmax/logp/self-dot, 4 threads/row (64 rows/blk),
//               [192,290) weight repack -> B-frag order, 290 smalls + flag.
//  K2 klmlp: fused KL + 6-layer MLP per 16-row tile (768 blocks, 256 thr,
//               47.6KB LDS -> 3 blocks/CU = grid exactly one dispatch round).
// Experiment record (all single-variable, all regressed -> reverted):
//  R8  mega-fusion + atomic grid barrier: 199us (barrier spin storm)
//  R11 8 waves/block lb(512,4): 148us (2 blocks/CU -> 1.5 dispatch rounds)
//  R12 jp unroll 2 (+misc): 143.3us (B-frag live-range doubling vs VGPR cap)
//  R13 MFMA chain splits: 142.7us (4x live accumulators vs VGPR cap)
// Conclusion: klmlp sits at the occupancy/register knee; R10 structure is
// the empirical optimum. Remaining time is harness-fixed (41us poison fill
// + reset dispatches) + two latency-bound kernels at their knee.

namespace {

constexpr int Nn = 1536, TOUT = 12;

typedef __attribute__((ext_vector_type(8))) short bf8;
typedef __attribute__((ext_vector_type(4))) float f4;
typedef unsigned short ush;

__device__ __forceinline__ float b2f(__hip_bfloat16 v) { return __bfloat162float(v); }
__device__ __forceinline__ ush f2bu(float f) {
  union { __hip_bfloat16 h; ush u; } c; c.h = __float2bfloat16(f); return c.u;
}
__device__ __forceinline__ float bu2f(ush u) {
  union { unsigned int i; float f; } c; c.i = ((unsigned)u) << 16; return c.f;
}
__device__ __forceinline__ float ldraw(const void* p, size_t i, int fl) {
  return fl ? ((const float*)p)[i] : b2f(((const __hip_bfloat16*)p)[i]);
}

// block-local dtype sniff: bf16 N(0,1) never has exp-field >= 140; f32 read
// as ushorts has ~45% of low-halves >= 140.  4096 samples.
__device__ __forceinline__ int detect_fl(const void* x, int tid) {
  __shared__ int cnt;
  if (tid == 0) cnt = 0;
  __syncthreads();
  const ush* u = (const ush*)x;
  int c = 0;
#pragma unroll
  for (int s = 0; s < 16; ++s) {
    ush v = u[tid + s * 256];
    if (((v >> 7) & 0xFF) >= 140) c++;
  }
  atomicAdd(&cnt, c);
  __syncthreads();
  return (cnt > 64) ? 1 : 0;
}

struct SmallTab { const void* src[16]; int n[16]; int off[16]; };
struct RepTab { const void* src[8]; int Nc[8]; int NCT[8]; int lb[9]; };

// ---------------- K1: prep + repack + smalls ---------------------------------
__global__ __launch_bounds__(256) void prep_all(
    const void* __restrict__ xraw, SmallTab st, RepTab rt,
    int* __restrict__ flag, float* __restrict__ CS,
    float* __restrict__ sd,
    ush* __restrict__ phi16, ush* __restrict__ plo16,
    ush* __restrict__ lhi16, ush* __restrict__ llo16,
    ush* __restrict__ Xc, ush* __restrict__ Wf) {
  __shared__ float lvs[64][12];
  int tid = threadIdx.x;
  int fl = detect_fl(xraw, tid);
  int blk = blockIdx.x;

  if (blk < 192) {
    // ---- prep role: 64 rows/block, 4 threads per row ----
    int rl = tid >> 2, sub = tid & 3;
    int row = blk * 64 + rl;
    int b = row / Nn, nn = row - b * Nn;   // 24 blocks/batch, no straddle
    float xv[12];
#pragma unroll
    for (int t = 0; t < 12; ++t)
      xv[t] = ldraw(xraw, (size_t)(b * 12 + t) * Nn + nn, fl);
    // redundant per-sub, bit-identical sequential order
    float mx = xv[0];
#pragma unroll
    for (int t = 1; t < 12; ++t) mx = fmaxf(mx, xv[t]);
    float e[12], Z = 0.f;
#pragma unroll
    for (int t = 0; t < 12; ++t) { e[t] = expf(xv[t] - mx); Z += e[t]; }
    float invZ = 1.f / Z;
    // each sub owns t = sub*3 .. sub*3+2: log + splits + stores
#pragma unroll
    for (int u = 0; u < 3; ++u) {
      int t = sub * 3 + u;
      float pv = e[t] * invZ;
      float lv = logf(pv + 1e-10f);
      lvs[rl][t] = lv;
      ush phv = f2bu(pv);  float plv = pv - bu2f(phv);
      ush lhv = f2bu(lv);  float llv = lv - bu2f(lhv);
      phi16[(size_t)row * 16 + t] = phv;
      plo16[(size_t)row * 16 + t] = f2bu(plv);
      lhi16[(size_t)row * 16 + t] = lhv;
      llo16[(size_t)row * 16 + t] = f2bu(llv);
      Xc[((size_t)(b * 16 + t)) * Nn + nn] = f2bu(xv[t]);
    }
    {  // pads: t = 12+sub for all arrays; Xc ones col at t=12
      int t = 12 + sub;
      phi16[(size_t)row * 16 + t] = 0;
      plo16[(size_t)row * 16 + t] = 0;
      lhi16[(size_t)row * 16 + t] = 0;
      llo16[(size_t)row * 16 + t] = 0;
      Xc[((size_t)(b * 16 + t)) * Nn + nn] = (sub == 0) ? (ush)0x3F80 : (ush)0;
    }
    __syncthreads();
    if (sub == 0) {
      float sacc = 0.f;
#pragma unroll
      for (int t = 0; t < 12; ++t)
        sacc = fmaf(e[t] * invZ, lvs[rl][t], sacc);
      sd[row] = sacc;
    }
  } else if (blk < 290) {
    // ---- repack role: weights -> MFMA B-frag order ----
    int idx = (blk - 192) * 256 + tid;
    if (idx >= rt.lb[8]) return;
    int mi = 0;
#pragma unroll
    for (int i = 1; i < 8; ++i) if (idx >= rt.lb[i]) mi = i;
    int li = idx - rt.lb[mi];
    int NCT = rt.NCT[mi], Nc = rt.Nc[mi];
    int per = NCT * 64;
    int c0 = li / per, rem = li - c0 * per;
    int ct = rem >> 6, l = rem & 63;
    int q = l >> 4, m = l & 15;
    int col = ct * 16 + m;
    ush* d = Wf + (size_t)idx * 8;
#pragma unroll
    for (int j = 0; j < 8; ++j) {
      int k = c0 * 32 + q * 8 + j;
      d[j] = (col < Nc) ? f2bu(ldraw(rt.src[mi], (size_t)k * Nc + col, fl)) : 0;
    }
  } else {
    // ---- smalls role: canonicalize biases/BN params to f32 + publish flag ----
    for (int i = 0; i < 16; ++i)
      for (int e = tid; e < st.n[i]; e += 256)
        CS[st.off[i] + e] = ldraw(st.src[i], e, fl);
    if (tid == 0) flag[0] = fl;
  }
}

// ---------------- K2: fused KL + MLP per 16-row tile -------------------------
__global__ __launch_bounds__(256, 3) void klmlp(
    const void* __restrict__ xraw,
    const ush* __restrict__ phi16, const ush* __restrict__ plo16,
    const ush* __restrict__ lhi16, const ush* __restrict__ llo16,
    const ush* __restrict__ Xc, const float* __restrict__ sd,
    const float* __restrict__ CS, const ush* __restrict__ Wf,
    const int* __restrict__ flag, void* __restrict__ outp) {
  __shared__ float xs[16][12], ccs[16][12];
  __shared__ float sfs[16][16], sbs[16][16];
  __shared__ float ws1[64], ws2[64];
  __shared__ ush hf[2048], hg[2048], xf[1024];
  __shared__ f4 red[4][64], red2[4][64];
  __shared__ union { ush T[2][4][512]; ush zf[12288]; } u;   // 24 KB alias

  int tid = threadIdx.x, w = tid >> 6, l = tid & 63, q = l >> 4, n = l & 15;
  int bi = blockIdx.x;
  int r0 = bi * 16;
  int b = bi / 96;            // 96 blocks per batch (1536/16)
  int rowb = b * Nn;
  int fl = flag[0];

  // xs staging overlaps phase B (independent loads)
  if (tid < 192) {
    int rr = tid / 12, tt = tid - rr * 12;
    xs[rr][tt] = ldraw(xraw, (size_t)(b * 12 + tt) * Nn + (r0 - rowb + rr), fl);
  }

  // ================= Phase B: KL + aggregation, 4 waves split j =============
  {
    bf8 z8 = {0, 0, 0, 0, 0, 0, 0, 0};
    // A-frags straight from the hi/lo row arrays: k<16 -> hi, k>=16 -> lo
    bf8 aP = (q < 2)
        ? *(const bf8*)(phi16 + ((size_t)(r0 + n)) * 16 + q * 8)
        : *(const bf8*)(plo16 + ((size_t)(r0 + n)) * 16 + (q - 2) * 8);
    bf8 aL = (q < 2)
        ? *(const bf8*)(lhi16 + ((size_t)(r0 + n)) * 16 + q * 8)
        : *(const bf8*)(llo16 + ((size_t)(r0 + n)) * 16 + (q - 2) * 8);
    bf8 aPh = (q < 2) ? aP : z8;
    bf8 aLh = (q < 2) ? aL : z8;
    float selfI[4];
#pragma unroll
    for (int r = 0; r < 4; ++r) selfI[r] = sd[r0 + q * 4 + r];

    f4 accF = {0.f, 0.f, 0.f, 0.f}, accB = {0.f, 0.f, 0.f, 0.f};

    for (int jp = 0; jp < 12; ++jp) {
      int jl = w * 384 + jp * 32;
#pragma unroll
      for (int hh = 0; hh < 2; ++hh) {
        int jh = jl + hh * 16;
        size_t bb = ((size_t)(rowb + jh + n)) * 16 + (q & 1) * 8;
        bf8 bLh = *(const bf8*)(lhi16 + bb);
        bf8 bLo = *(const bf8*)(llo16 + bb);
        bf8 bPh = *(const bf8*)(phi16 + bb);
        bf8 bPo = *(const bf8*)(plo16 + bb);
        float selfJ = sd[rowb + jh + n];

        f4 s1 = {0.f, 0.f, 0.f, 0.f}, s2 = {0.f, 0.f, 0.f, 0.f};
        s1 = __builtin_amdgcn_mfma_f32_16x16x32_bf16(aP, bLh, s1, 0, 0, 0);
        s1 = __builtin_amdgcn_mfma_f32_16x16x32_bf16(aPh, bLo, s1, 0, 0, 0);
        s2 = __builtin_amdgcn_mfma_f32_16x16x32_bf16(aL, bPh, s2, 0, 0, 0);
        s2 = __builtin_amdgcn_mfma_f32_16x16x32_bf16(aLh, bPo, s2, 0, 0, 0);

        int qk = n >> 3, kj = n & 7;
#pragma unroll
        for (int r = 0; r < 4; ++r) {
          int pos = hh * 256 + (qk * 16 + q * 4 + r) * 8 + kj;
          u.T[0][w][pos] = (selfI[r] - s1[r] < 0.5f) ? (ush)0x3F80 : (ush)0;
          u.T[1][w][pos] = (selfJ - s2[r] < 0.5f) ? (ush)0x3F80 : (ush)0;
        }
      }
      bf8 af1 = *(const bf8*)(&u.T[0][w][(size_t)l * 8]);
      bf8 af2 = *(const bf8*)(&u.T[1][w][(size_t)l * 8]);
      bf8 xfr = *(const bf8*)(Xc + ((size_t)(b * 16 + n)) * Nn + jl + q * 8);
      accF = __builtin_amdgcn_mfma_f32_16x16x32_bf16(af1, xfr, accF, 0, 0, 0);
      accB = __builtin_amdgcn_mfma_f32_16x16x32_bf16(af2, xfr, accB, 0, 0, 0);
    }
    red[w][l] = accF;
    red2[w][l] = accB;
  }
  __syncthreads();

  // j-split reduction -> sfs/sbs; waves 2,3 stage W1/W2 meanwhile
  if (w == 0) {
    f4 s = red[0][l] + red[1][l] + red[2][l] + red[3][l];
#pragma unroll
    for (int r = 0; r < 4; ++r) sfs[q * 4 + r][n] = s[r];
  } else if (w == 1) {
    f4 s = red2[0][l] + red2[1][l] + red2[2][l] + red2[3][l];
#pragma unroll
    for (int r = 0; r < 4; ++r) sbs[q * 4 + r][n] = s[r];
  } else if (w == 2) {
    ws1[l] = CS[l];
  } else {
    ws2[l] = CS[64 + l];
  }
  __syncthreads();
  if (tid < 192) {
    int rr = tid / 12, tt = tid - rr * 12;
    float irs = 1.f / fmaxf(sfs[rr][12], 1e-6f);
    float ics = 1.f / fmaxf(sbs[rr][12], 1e-6f);
    ccs[rr][tt] = 3.0f * (0.3f * sfs[rr][tt] * irs + 0.7f * sbs[rr][tt] * ics);
  }
  __syncthreads();

  // ================= Phase C: fused MLP ====================================
  // z A-frag regen: row = r0+n, k = c0*32 + q*8 + j
  auto zregen = [&](int c0) -> bf8 {
    int t = c0 >> 1, h0 = (c0 & 1) * 32 + q * 8;
    float xv = xs[n][t], cv = ccs[n][t];
    union { bf8 v; ush uu[8]; } au;
#pragma unroll
    for (int j = 0; j < 8; ++j)
      au.uu[j] = f2bu(fmaxf(fmaf(xv, ws1[h0 + j], cv * ws2[h0 + j]), 0.f));
    return au.v;
  };
  auto fpos = [&](int ct, int r) -> int {
    return ((ct >> 1) * 64 + ((ct & 1) * 2 + (n >> 3)) * 16 + q * 4 + r) * 8 + (n & 7);
  };

  // fill the z-frag cache (aliases T; all T reads are done): wave w owns 6 c0s
#pragma unroll
  for (int u6 = 0; u6 < 6; ++u6) {
    int c0 = w * 6 + u6;
    bf8 v = zregen(c0);
    *(bf8*)(&u.zf[((size_t)c0 * 64 + l) * 8]) = v;
  }
  __syncthreads();

  // --- L1e: h1 = relu(z @ ew1 + b1), N=128, wave does ct = 2w, 2w+1 --------
  {
    f4 a0 = {0.f, 0.f, 0.f, 0.f}, a1 = {0.f, 0.f, 0.f, 0.f};
    for (int c0 = 0; c0 < 24; ++c0) {
      bf8 a = *(const bf8*)(&u.zf[((size_t)c0 * 64 + l) * 8]);
      const ush* wb = Wf + ((size_t)(c0 * 8 + 2 * w) * 64 + l) * 8;
      bf8 b0 = *(const bf8*)wb;
      bf8 b1 = *(const bf8*)(wb + 512);
      a0 = __builtin_amdgcn_mfma_f32_16x16x32_bf16(a, b0, a0, 0, 0, 0);
      a1 = __builtin_amdgcn_mfma_f32_16x16x32_bf16(a, b1, a1, 0, 0, 0);
    }
#pragma unroll
    for (int u2 = 0; u2 < 2; ++u2) {
      int ct = 2 * w + u2;
      f4 acc = u2 ? a1 : a0;
      float bz = CS[128 + ct * 16 + n];
#pragma unroll
      for (int r = 0; r < 4; ++r)
        hf[fpos(ct, r)] = f2bu(fmaxf(acc[r] + bz, 0.f));
    }
  }
  __syncthreads();

  // --- L2e: h2 = relu(h1 @ ew2 + b2), K=128 --------------------------------
  {
    f4 a0 = {0.f, 0.f, 0.f, 0.f}, a1 = {0.f, 0.f, 0.f, 0.f};
    for (int c0 = 0; c0 < 4; ++c0) {
      bf8 a = *(const bf8*)(&hf[(size_t)(c0 * 64 + l) * 8]);
      const ush* wb = Wf + 98304 + ((size_t)(c0 * 8 + 2 * w) * 64 + l) * 8;
      bf8 b0 = *(const bf8*)wb;
      bf8 b1 = *(const bf8*)(wb + 512);
      a0 = __builtin_amdgcn_mfma_f32_16x16x32_bf16(a, b0, a0, 0, 0, 0);
      a1 = __builtin_amdgcn_mfma_f32_16x16x32_bf16(a, b1, a1, 0, 0, 0);
    }
    __syncthreads();   // hf reads complete before later rewrite
#pragma unroll
    for (int u2 = 0; u2 < 2; ++u2) {
      int ct = 2 * w + u2;
      f4 acc = u2 ? a1 : a0;
      float bz = CS[256 + ct * 16 + n];
#pragma unroll
      for (int r = 0; r < 4; ++r)
        hg[fpos(ct, r)] = f2bu(fmaxf(acc[r] + bz, 0.f));
    }
  }
  __syncthreads();

  // --- L3e: xe = BN(h2 @ ew3 + b3 + z @ eproj), N=64, wave does ct = w -----
  {
    f4 a3 = {0.f, 0.f, 0.f, 0.f};
    for (int c0 = 0; c0 < 4; ++c0) {
      bf8 a = *(const bf8*)(&hg[(size_t)(c0 * 64 + l) * 8]);
      bf8 bb = *(const bf8*)(Wf + 114688 + ((size_t)(c0 * 4 + w) * 64 + l) * 8);
      a3 = __builtin_amdgcn_mfma_f32_16x16x32_bf16(a, bb, a3, 0, 0, 0);
    }
    for (int c0 = 0; c0 < 24; ++c0) {
      bf8 a = *(const bf8*)(&u.zf[((size_t)c0 * 64 + l) * 8]);
      bf8 bb = *(const bf8*)(Wf + 122880 + ((size_t)(c0 * 4 + w) * 64 + l) * 8);
      a3 = __builtin_amdgcn_mfma_f32_16x16x32_bf16(a, bb, a3, 0, 0, 0);
    }
    int col = w * 16 + n;
    float g = CS[448 + col], be = CS[512 + col], mm = CS[576 + col], vv = CS[640 + col];
    float sc = g / sqrtf(vv + 1e-5f);
    float sh = be - mm * sc;
    float bz = CS[384 + col];
#pragma unroll
    for (int r = 0; r < 4; ++r)
      xf[fpos(w, r)] = f2bu((a3[r] + bz) * sc + sh);
  }
  __syncthreads();

  // --- L1d: g1 = relu(xe @ dw1 + b1), K=64, N=128 --------------------------
  {
    f4 a0 = {0.f, 0.f, 0.f, 0.f}, a1 = {0.f, 0.f, 0.f, 0.f};
    for (int c0 = 0; c0 < 2; ++c0) {
      bf8 a = *(const bf8*)(&xf[(size_t)(c0 * 64 + l) * 8]);
      const ush* wb = Wf + 172032 + ((size_t)(c0 * 8 + 2 * w) * 64 + l) * 8;
      bf8 b0 = *(const bf8*)wb;
      bf8 b1 = *(const bf8*)(wb + 512);
      a0 = __builtin_amdgcn_mfma_f32_16x16x32_bf16(a, b0, a0, 0, 0, 0);
      a1 = __builtin_amdgcn_mfma_f32_16x16x32_bf16(a, b1, a1, 0, 0, 0);
    }
    __syncthreads();   // hf rewrite fence
#pragma unroll
    for (int u2 = 0; u2 < 2; ++u2) {
      int ct = 2 * w + u2;
      f4 acc = u2 ? a1 : a0;
      float bz = CS[704 + ct * 16 + n];
#pragma unroll
      for (int r = 0; r < 4; ++r)
        hf[fpos(ct, r)] = f2bu(fmaxf(acc[r] + bz, 0.f));
    }
  }
  __syncthreads();

  // --- L2d: g2 = relu(g1 @ dw2 + b2), K=128 --------------------------------
  {
    f4 a0 = {0.f, 0.f, 0.f, 0.f}, a1 = {0.f, 0.f, 0.f, 0.f};
    for (int c0 = 0; c0 < 4; ++c0) {
      bf8 a = *(const bf8*)(&hf[(size_t)(c0 * 64 + l) * 8]);
      const ush* wb = Wf + 180224 + ((size_t)(c0 * 8 + 2 * w) * 64 + l) * 8;
      bf8 b0 = *(const bf8*)wb;
      bf8 b1 = *(const bf8*)(wb + 512);
      a0 = __builtin_amdgcn_mfma_f32_16x16x32_bf16(a, b0, a0, 0, 0, 0);
      a1 = __builtin_amdgcn_mfma_f32_16x16x32_bf16(a, b1, a1, 0, 0, 0);
    }
    __syncthreads();   // hg rewrite fence
#pragma unroll
    for (int u2 = 0; u2 < 2; ++u2) {
      int ct = 2 * w + u2;
      f4 acc = u2 ? a1 : a0;
      float bz = CS[832 + ct * 16 + n];
#pragma unroll
      for (int r = 0; r < 4; ++r)
        hg[fpos(ct, r)] = f2bu(fmaxf(acc[r] + bz, 0.f));
    }
  }
  __syncthreads();

  // --- L3d: out = BN(g2 @ dw3 + b3 + xe @ dproj), N=12; K-split 4 waves ----
  {
    f4 ao = {0.f, 0.f, 0.f, 0.f};
    {  // dw3 chunk c0 = w  (K=128 -> 4 chunks)
      bf8 a = *(const bf8*)(&hg[(size_t)(w * 64 + l) * 8]);
      bf8 bb = *(const bf8*)(Wf + 196608 + ((size_t)w * 64 + l) * 8);
      ao = __builtin_amdgcn_mfma_f32_16x16x32_bf16(a, bb, ao, 0, 0, 0);
    }
    if (w < 2) {  // dproj chunk c0 = w  (K=64 -> 2 chunks)
      bf8 a = *(const bf8*)(&xf[(size_t)(w * 64 + l) * 8]);
      bf8 bb = *(const bf8*)(Wf + 198656 + ((size_t)w * 64 + l) * 8);
      ao = __builtin_amdgcn_mfma_f32_16x16x32_bf16(a, bb, ao, 0, 0, 0);
    }
    red[w][l] = ao;
  }
  __syncthreads();
  if (w == 0) {
    f4 s = red[0][l] + red[1][l] + red[2][l] + red[3][l];
    if (n < 12) {
      float bz = CS[960 + n];
      float g = CS[972 + n], be = CS[984 + n], mm = CS[996 + n], vv = CS[1008 + n];
      float sc = g / sqrtf(vv + 1e-5f);
      float sh = be - mm * sc;
#pragma unroll
      for (int r = 0; r < 4; ++r) {
        int row = r0 + q * 4 + r;
        int bb2 = row / Nn, nn2 = row - bb2 * Nn;
        size_t oi = ((size_t)bb2 * TOUT + n) * Nn + nn2;
        float ov = (s[r] + bz) * sc + sh;
        if (fl) ((float*)outp)[oi] = ov;
        else    ((ush*)outp)[oi] = f2bu(ov);
      }
    }
  }
}

}  // namespace

extern "C" void kernel_launch(void* const* d_in, const int* in_sizes, int n_in,
                              void* d_out, int out_size, void* d_ws, size_t ws_size,
                              hipStream_t stream) {
  float* f = (float*)d_ws;
  int* flag = (int*)d_ws;                 // f[0..15]
  float* CS  = f + 16;                    // 1020 small params (f32)
  float* sd  = f + 1040;                  // 12288
  ush* U = (ush*)(f + 13328);
  ush* phi16 = U;                         // 12288*16
  ush* plo16 = U + 196608;
  ush* lhi16 = U + 393216;
  ush* llo16 = U + 589824;
  ush* Xc    = U + 786432;                // 8*16*1536
  ush* Wf    = U + 983040;                // 199680

  SmallTab st;
  {
    const int idxs[16] = {1, 2, 4, 6, 8, 10, 11, 12, 13, 15, 17, 19, 21, 22, 23, 24};
    const int ns[16]   = {64, 64, 128, 128, 64, 64, 64, 64, 64, 128, 128, 12, 12, 12, 12, 12};
    int off = 0;
    for (int i = 0; i < 16; ++i) {
      st.src[i] = d_in[idxs[i]]; st.n[i] = ns[i]; st.off[i] = off; off += ns[i];
    }
  }
  RepTab rt;
  {
    const int idxs[8]  = {3, 5, 7, 9, 14, 16, 18, 20};
    const int rNc[8]   = {128, 128, 64, 64, 128, 128, 12, 12};
    const int rNCT[8]  = {8, 8, 4, 4, 8, 8, 1, 1};
    const int rlb[9]   = {0, 12288, 14336, 15360, 21504, 22528, 24576, 24832, 24960};
    for (int i = 0; i < 8; ++i) {
      rt.src[i] = d_in[idxs[i]]; rt.Nc[i] = rNc[i]; rt.NCT[i] = rNCT[i];
    }
    for (int i = 0; i < 9; ++i) rt.lb[i] = rlb[i];
  }

  prep_all<<<291, 256, 0, stream>>>(d_in[0], st, rt, flag, CS, sd,
                                    phi16, plo16, lhi16, llo16, Xc, Wf);
  klmlp<<<768, 256, 0, stream>>>(d_in[0], phi16, plo16, lhi16, llo16,
                                 Xc, sd, CS, Wf, flag, d_out);
}